// Round 3
// baseline (3377.103 us; speedup 1.0000x reference)
//
#include <hip/hip_runtime.h>
#include <hip/hip_bf16.h>

// HeteroGraphSAGE on MI355X — round 2 (identical resubmit; rounds 0-1 never
// ran: GPUAcquisitionTimeout both times, no counters, no correctness signal).
//
// Structure per call:
//   1. Build CSR (dst-sorted adjacency) for all 6 relations once; reused by 4 layers.
//   2. Per layer, per dst type: gather-mean (2 relations) -> fused 3-term GEMM
//      out = relu?(0.5*(aggA@WlA + aggB@WlB + h@(WrA+WrB) + bA+bB))
//   3. Row L2-normalize into d_out.
//
// Workspace budget ~115.6 MB (hbuf0 46.1 + agg 51.2 + csr 16 + misc). d_out is
// used as the second h ping-pong buffer (layer 1/3 output), normalized in place.

#define NC_N 50000
#define NM_N 30000
#define ND_N 10000
#define NTOT 90000
#define H    128

// ---------------------------------------------------------------- CSR build
__global__ void count_k(const int* __restrict__ dst, int E, int* __restrict__ cnt) {
    int i = blockIdx.x * blockDim.x + threadIdx.x;
    if (i < E) atomicAdd(&cnt[dst[i]], 1);
}

__global__ void scan_k(const int* __restrict__ cnt, int* __restrict__ offs, int n) {
    __shared__ int buf[1024];
    __shared__ int s_carry;
    int tid = threadIdx.x;
    if (tid == 0) { s_carry = 0; offs[0] = 0; }
    __syncthreads();
    for (int base = 0; base < n; base += 1024) {
        int i = base + tid;
        int v = (i < n) ? cnt[i] : 0;
        buf[tid] = v;
        __syncthreads();
        #pragma unroll
        for (int off = 1; off < 1024; off <<= 1) {
            int t = (tid >= off) ? buf[tid - off] : 0;
            __syncthreads();
            buf[tid] += t;
            __syncthreads();
        }
        int incl = buf[tid] + s_carry;   // inclusive prefix incl. carry
        if (i < n) offs[i + 1] = incl;
        __syncthreads();
        if (tid == 0) s_carry += buf[1023];
        __syncthreads();
    }
}

__global__ void fill_k(const int* __restrict__ src, const int* __restrict__ dst, int E,
                       const int* __restrict__ offs, int* __restrict__ cur,
                       int* __restrict__ csr) {
    int i = blockIdx.x * blockDim.x + threadIdx.x;
    if (i < E) {
        int d = dst[i];
        int p = atomicAdd(&cur[d], 1);
        csr[offs[d] + p] = src[i];
    }
}

// ------------------------------------------------------- weight precombine
// Wsum[l][t] = Wr[l][rA(t)] + Wr[l][rB(t)];  bsum[l][t] = b[l][rA]+b[l][rB]
__global__ void combine_k(const float* __restrict__ Wr, const float* __restrict__ b,
                          float* __restrict__ Wsum, float* __restrict__ bsum) {
    const int rA[3] = {3, 0, 1}, rB[3] = {5, 4, 2};
    int idx = blockIdx.x * blockDim.x + threadIdx.x;
    const int totalW = 4 * 3 * H * H;
    if (idx < totalW) {
        int lt = idx >> 14;        // l*3+t
        int e  = idx & 16383;
        int l = lt / 3, t = lt % 3;
        Wsum[idx] = Wr[(size_t)(l * 6 + rA[t]) * H * H + e] +
                    Wr[(size_t)(l * 6 + rB[t]) * H * H + e];
    }
    if (idx < 4 * 3 * H) {
        int lt = idx >> 7;
        int e  = idx & 127;
        int l = lt / 3, t = lt % 3;
        bsum[idx] = b[(l * 6 + rA[t]) * H + e] + b[(l * 6 + rB[t]) * H + e];
    }
}

// ----------------------------------------------------------- segment mean
// one wave per dst node; lane covers features 2*lane, 2*lane+1 (float2)
__global__ __launch_bounds__(256)
void agg_k(const float* __restrict__ hsrc, const int* __restrict__ offs,
           const int* __restrict__ csr, float* __restrict__ agg, int n) {
    int w    = (blockIdx.x * 256 + threadIdx.x) >> 6;
    int lane = threadIdx.x & 63;
    if (w >= n) return;
    int s = offs[w], e = offs[w + 1];
    float a0 = 0.f, a1 = 0.f;
    for (int j = s; j < e; ++j) {
        const float2 v = *(const float2*)(hsrc + (size_t)csr[j] * H + lane * 2);
        a0 += v.x; a1 += v.y;
    }
    float inv = 1.0f / fmaxf((float)(e - s), 1.0f);
    float2 o; o.x = a0 * inv; o.y = a1 * inv;
    *(float2*)(agg + (size_t)w * H + lane * 2) = o;
}

// ------------------------------------------------------------ fused GEMM
// out[n x 128] = maybe_relu(0.5*(A1@W1 + A2@W2 + A3@W3 + bias))
#define GBM 64
#define GBK 32
__global__ __launch_bounds__(256)
void gemm3_k(int n,
             const float* __restrict__ A1, const float* __restrict__ W1,
             const float* __restrict__ A2, const float* __restrict__ W2,
             const float* __restrict__ A3, const float* __restrict__ W3,
             const float* __restrict__ bias, float* __restrict__ out, int relu) {
    __shared__ float Ast[GBK][GBM + 4];   // transposed A tile (16B-aligned rows)
    __shared__ float Ws[GBK][H];
    const int tid  = threadIdx.x;
    const int tx   = tid & 15;    // col group: cols tx*8..+7
    const int ty   = tid >> 4;    // row group: rows ty*4..+3
    const int row0 = blockIdx.x * GBM;

    float acc[4][8];
    #pragma unroll
    for (int i = 0; i < 4; ++i)
        #pragma unroll
        for (int j = 0; j < 8; ++j) acc[i][j] = 0.f;

    const float* Ap[3] = {A1, A2, A3};
    const float* Wp[3] = {W1, W2, W3};

    for (int term = 0; term < 3; ++term) {
        const float* A = Ap[term];
        const float* W = Wp[term];
        #pragma unroll 1
        for (int k0 = 0; k0 < H; k0 += GBK) {
            // A tile (transposed into LDS): 64 rows x 32 k
            #pragma unroll
            for (int f = tid; f < GBM * GBK / 4; f += 256) {
                int r = f >> 3, c4 = f & 7;
                int gr = row0 + r;
                float4 v = (gr < n) ? *(const float4*)(A + (size_t)gr * H + k0 + c4 * 4)
                                    : make_float4(0.f, 0.f, 0.f, 0.f);
                Ast[c4 * 4 + 0][r] = v.x; Ast[c4 * 4 + 1][r] = v.y;
                Ast[c4 * 4 + 2][r] = v.z; Ast[c4 * 4 + 3][r] = v.w;
            }
            // W tile: 32 k x 128 cols
            #pragma unroll
            for (int f = tid; f < GBK * H / 4; f += 256) {
                int r = f >> 5, c4 = f & 31;
                *(float4*)&Ws[r][c4 * 4] = *(const float4*)(W + (size_t)(k0 + r) * H + c4 * 4);
            }
            __syncthreads();
            #pragma unroll
            for (int kk = 0; kk < GBK; ++kk) {
                float4 av = *(const float4*)&Ast[kk][ty * 4];
                float4 w0 = *(const float4*)&Ws[kk][tx * 8];
                float4 w1 = *(const float4*)&Ws[kk][tx * 8 + 4];
                float a[4] = {av.x, av.y, av.z, av.w};
                float w[8] = {w0.x, w0.y, w0.z, w0.w, w1.x, w1.y, w1.z, w1.w};
                #pragma unroll
                for (int i = 0; i < 4; ++i)
                    #pragma unroll
                    for (int j = 0; j < 8; ++j)
                        acc[i][j] = fmaf(a[i], w[j], acc[i][j]);
            }
            __syncthreads();
        }
    }
    #pragma unroll
    for (int i = 0; i < 4; ++i) {
        int gr = row0 + ty * 4 + i;
        if (gr < n) {
            float* orow = out + (size_t)gr * H + tx * 8;
            #pragma unroll
            for (int j = 0; j < 8; ++j) {
                float v = 0.5f * (acc[i][j] + bias[tx * 8 + j]);
                if (relu) v = fmaxf(v, 0.f);
                orow[j] = v;
            }
        }
    }
}

// -------------------------------------------------------------- L2 norm
__global__ __launch_bounds__(256)
void norm_k(const float* __restrict__ h, float* __restrict__ out, int n) {
    int w    = (blockIdx.x * 256 + threadIdx.x) >> 6;
    int lane = threadIdx.x & 63;
    if (w >= n) return;
    const float2 v = *(const float2*)(h + (size_t)w * H + lane * 2);
    float ss = v.x * v.x + v.y * v.y;
    #pragma unroll
    for (int off = 32; off; off >>= 1) ss += __shfl_xor(ss, off);
    float scale = 1.0f / fmaxf(sqrtf(ss), 1e-12f);
    float2 o; o.x = v.x * scale; o.y = v.y * scale;
    *(float2*)(out + (size_t)w * H + lane * 2) = o;
}

// ---------------------------------------------------------------- launch
extern "C" void kernel_launch(void* const* d_in, const int* in_sizes, int n_in,
                              void* d_out, int out_size, void* d_ws, size_t ws_size,
                              hipStream_t stream) {
    const float* x[3] = {(const float*)d_in[0], (const float*)d_in[1], (const float*)d_in[2]};
    const int* srcp[6] = {(const int*)d_in[3], (const int*)d_in[5], (const int*)d_in[7],
                          (const int*)d_in[9], (const int*)d_in[11], (const int*)d_in[13]};
    const int* dstp[6] = {(const int*)d_in[4], (const int*)d_in[6], (const int*)d_in[8],
                          (const int*)d_in[10], (const int*)d_in[12], (const int*)d_in[14]};
    const float* Wl = (const float*)d_in[15];
    const float* Wr = (const float*)d_in[16];
    const float* b  = (const float*)d_in[17];
    float* outp = (float*)d_out;

    const int nNode[3]   = {NC_N, NM_N, ND_N};
    const int E[6]       = {800000, 400000, 800000, 800000, 400000, 800000};
    const int nDst[6]    = {NM_N, ND_N, ND_N, NC_N, NM_N, NC_N};
    const int srcType[6] = {0, 1, 0, 1, 2, 2};
    const int relA[3] = {3, 0, 1}, relB[3] = {5, 4, 2};   // dst type -> its 2 relations

    // ---- workspace carve-up (256B aligned), total ~115.6 MB
    char* p = (char*)d_ws;
    auto alloc = [&](size_t bytes) -> char* {
        char* r = p; p += (bytes + 255) & ~(size_t)255; return r;
    };
    float* hbuf0 = (float*)alloc((size_t)NTOT * H * 4);
    float* aggA  = (float*)alloc((size_t)NC_N * H * 4);
    float* aggB  = (float*)alloc((size_t)NC_N * H * 4);
    float* Wsum  = (float*)alloc((size_t)4 * 3 * H * H * 4);
    float* bsum  = (float*)alloc((size_t)4 * 3 * H * 4);
    int*   cnt   = (int*)alloc((size_t)180000 * 4);
    int*   offs  = (int*)alloc((size_t)180006 * 4);
    int*   csr   = (int*)alloc((size_t)4000000 * 4);
    float* hbuf1 = outp;   // reuse d_out as the odd ping-pong h buffer

    int offsBase[6], csrBase[6], cntBase[6];
    { int ob = 0, cb = 0, nb = 0;
      for (int r = 0; r < 6; ++r) {
          offsBase[r] = ob; ob += nDst[r] + 1;
          csrBase[r]  = cb; cb += E[r];
          cntBase[r]  = nb; nb += nDst[r];
      } }

    // ---- CSR build (once, reused by all layers)
    hipMemsetAsync(cnt, 0, 180000 * 4, stream);
    for (int r = 0; r < 6; ++r)
        count_k<<<(E[r] + 255) / 256, 256, 0, stream>>>(dstp[r], E[r], cnt + cntBase[r]);
    for (int r = 0; r < 6; ++r)
        scan_k<<<1, 1024, 0, stream>>>(cnt + cntBase[r], offs + offsBase[r], nDst[r]);
    hipMemsetAsync(cnt, 0, 180000 * 4, stream);   // reuse as fill cursors
    for (int r = 0; r < 6; ++r)
        fill_k<<<(E[r] + 255) / 256, 256, 0, stream>>>(srcp[r], dstp[r], E[r],
                                                       offs + offsBase[r],
                                                       cnt + cntBase[r],
                                                       csr + csrBase[r]);

    combine_k<<<(4 * 3 * H * H + 255) / 256, 256, 0, stream>>>(Wr, b, Wsum, bsum);

    const size_t tOff[3] = {0, (size_t)NC_N * H, (size_t)(NC_N + NM_N) * H};
    float* hb[2] = {hbuf0, hbuf1};

    int cur = -1, nxt = 0;
    for (int l = 0; l < 4; ++l) {
        float* dstBuf = hb[nxt];
        for (int t = 0; t < 3; ++t) {
            int rA = relA[t], rB = relB[t];
            const float* hsA = (l == 0) ? x[srcType[rA]] : hb[cur] + tOff[srcType[rA]];
            const float* hsB = (l == 0) ? x[srcType[rB]] : hb[cur] + tOff[srcType[rB]];
            const float* hT  = (l == 0) ? x[t]           : hb[cur] + tOff[t];
            int n = nNode[t];
            agg_k<<<(n + 3) / 4, 256, 0, stream>>>(hsA, offs + offsBase[rA],
                                                   csr + csrBase[rA], aggA, n);
            agg_k<<<(n + 3) / 4, 256, 0, stream>>>(hsB, offs + offsBase[rB],
                                                   csr + csrBase[rB], aggB, n);
            gemm3_k<<<(n + GBM - 1) / GBM, 256, 0, stream>>>(
                n,
                aggA, Wl + (size_t)(l * 6 + rA) * H * H,
                aggB, Wl + (size_t)(l * 6 + rB) * H * H,
                hT,   Wsum + (size_t)(l * 3 + t) * H * H,
                bsum + (size_t)(l * 3 + t) * H,
                dstBuf + tOff[t], (l < 3) ? 1 : 0);
        }
        cur = nxt; nxt ^= 1;
    }
    // final h is in hb[cur] (= d_out); normalize in place (row-local, safe)
    norm_k<<<(NTOT + 3) / 4, 256, 0, stream>>>(hb[cur], outp, NTOT);
}

// Round 4
// 2216.514 us; speedup vs baseline: 1.5236x; 1.5236x over previous
//
#include <hip/hip_runtime.h>
#include <hip/hip_bf16.h>

// HeteroGraphSAGE on MI355X — round 3.
// Round-2 profile: agg_k = 62% of 3.38ms, latency-bound (VALUBusy 8.7%, HBM 21%).
// Changes:
//   * agg2_k: 4-deep MLP gather — float4/lane, half-wave edge pairing, 8 edges
//     in flight per iter; A+B relations of a dst type merged into one dispatch.
//   * CSR build: count/fill merged into single grid-partitioned launches;
//     the 6 prefix scans run concurrently as 6 blocks of one kernel.
//   * gemm3_k / combine_k / norm_k unchanged (await their counters).

#define NC_N 50000
#define NM_N 30000
#define ND_N 10000
#define NTOT 90000
#define H    128

// ---------------------------------------------------------------- CSR build
struct BuildArgs {
    const int* dstp[6];
    const int* srcp[6];
    int blockBase[7];   // prefix over ceil(E[r]/256)
    int E[6];
    int cntBase[6];
    int offsBase[6];
    int csrBase[6];
    int nDst[6];
};

__global__ void count_all_k(BuildArgs a, int* __restrict__ cnt) {
    int b = blockIdx.x, r = 0;
    #pragma unroll
    for (int k = 1; k <= 5; ++k) if (b >= a.blockBase[k]) r = k;
    int i = (b - a.blockBase[r]) * 256 + threadIdx.x;
    if (i < a.E[r]) atomicAdd(&cnt[a.cntBase[r] + a.dstp[r][i]], 1);
}

__global__ void scan_all_k(BuildArgs a, const int* __restrict__ cnt,
                           int* __restrict__ offsAll) {
    const int r = blockIdx.x;                 // one block per relation
    const int* c = cnt + a.cntBase[r];
    int* offs = offsAll + a.offsBase[r];
    const int n = a.nDst[r];
    __shared__ int buf[1024];
    __shared__ int s_carry;
    int tid = threadIdx.x;
    if (tid == 0) { s_carry = 0; offs[0] = 0; }
    __syncthreads();
    for (int base = 0; base < n; base += 1024) {
        int i = base + tid;
        int v = (i < n) ? c[i] : 0;
        buf[tid] = v;
        __syncthreads();
        #pragma unroll
        for (int off = 1; off < 1024; off <<= 1) {
            int t = (tid >= off) ? buf[tid - off] : 0;
            __syncthreads();
            buf[tid] += t;
            __syncthreads();
        }
        int incl = buf[tid] + s_carry;
        if (i < n) offs[i + 1] = incl;
        __syncthreads();
        if (tid == 0) s_carry += buf[1023];
        __syncthreads();
    }
}

__global__ void fill_all_k(BuildArgs a, const int* __restrict__ offs,
                           int* __restrict__ cur, int* __restrict__ csr) {
    int b = blockIdx.x, r = 0;
    #pragma unroll
    for (int k = 1; k <= 5; ++k) if (b >= a.blockBase[k]) r = k;
    int i = (b - a.blockBase[r]) * 256 + threadIdx.x;
    if (i < a.E[r]) {
        int d = a.dstp[r][i];
        int p = atomicAdd(&cur[a.cntBase[r] + d], 1);
        csr[a.csrBase[r] + offs[a.offsBase[r] + d] + p] = a.srcp[r][i];
    }
}

// ------------------------------------------------------- weight precombine
__global__ void combine_k(const float* __restrict__ Wr, const float* __restrict__ b,
                          float* __restrict__ Wsum, float* __restrict__ bsum) {
    const int rA[3] = {3, 0, 1}, rB[3] = {5, 4, 2};
    int idx = blockIdx.x * blockDim.x + threadIdx.x;
    const int totalW = 4 * 3 * H * H;
    if (idx < totalW) {
        int lt = idx >> 14;
        int e  = idx & 16383;
        int l = lt / 3, t = lt % 3;
        Wsum[idx] = Wr[(size_t)(l * 6 + rA[t]) * H * H + e] +
                    Wr[(size_t)(l * 6 + rB[t]) * H * H + e];
    }
    if (idx < 4 * 3 * H) {
        int lt = idx >> 7;
        int e  = idx & 127;
        int l = lt / 3, t = lt % 3;
        bsum[idx] = b[(l * 6 + rA[t]) * H + e] + b[(l * 6 + rB[t]) * H + e];
    }
}

// ----------------------------------------------------------- segment mean
// One wave per dst node. float4/lane: lanes 0..31 cover the 128 features of
// one edge row, lanes 32..63 the next edge. 8 edges (4 index loads + 4 row
// gathers) in flight per main-loop iter for memory-level parallelism.
__global__ __launch_bounds__(256)
void agg2_k(const float* __restrict__ srcA, const int* __restrict__ offsA,
            const int* __restrict__ csrA,
            const float* __restrict__ srcB, const int* __restrict__ offsB,
            const int* __restrict__ csrB,
            float* __restrict__ outA, float* __restrict__ outB,
            int n, int halfBlocks) {
    const int b = blockIdx.x;
    const bool isB = (b >= halfBlocks);
    const float* __restrict__ src = isB ? srcB : srcA;
    const int* __restrict__ offs  = isB ? offsB : offsA;
    const int* __restrict__ csr   = isB ? csrB : csrA;
    float* __restrict__ out       = isB ? outB : outA;
    const int w = (b - (isB ? halfBlocks : 0)) * 4 + (int)(threadIdx.x >> 6);
    if (w >= n) return;

    const int lane = threadIdx.x & 63;
    const int half = lane >> 5;          // which edge of the pair
    const int fc   = (lane & 31) * 4;    // feature column base (4 floats)
    const int s = offs[w], e = offs[w + 1];

    float ax = 0.f, ay = 0.f, az = 0.f, aw = 0.f;   // acc for even edges
    float bx = 0.f, by = 0.f, bz = 0.f, bw = 0.f;   // acc for odd edges
    int j = s;
    for (; j + 8 <= e; j += 8) {
        int i0 = csr[j + half];
        int i1 = csr[j + 2 + half];
        int i2 = csr[j + 4 + half];
        int i3 = csr[j + 6 + half];
        const float4 v0 = *(const float4*)(src + (size_t)i0 * H + fc);
        const float4 v1 = *(const float4*)(src + (size_t)i1 * H + fc);
        const float4 v2 = *(const float4*)(src + (size_t)i2 * H + fc);
        const float4 v3 = *(const float4*)(src + (size_t)i3 * H + fc);
        ax += v0.x; ay += v0.y; az += v0.z; aw += v0.w;
        bx += v1.x; by += v1.y; bz += v1.z; bw += v1.w;
        ax += v2.x; ay += v2.y; az += v2.z; aw += v2.w;
        bx += v3.x; by += v3.y; bz += v3.z; bw += v3.w;
    }
    for (; j + 2 <= e; j += 2) {
        int i0 = csr[j + half];
        const float4 v = *(const float4*)(src + (size_t)i0 * H + fc);
        ax += v.x; ay += v.y; az += v.z; aw += v.w;
    }
    if (j < e && half == 0) {            // single leftover edge
        int i0 = csr[j];
        const float4 v = *(const float4*)(src + (size_t)i0 * H + fc);
        ax += v.x; ay += v.y; az += v.z; aw += v.w;
    }
    float tx = ax + bx, ty = ay + by, tz = az + bz, tw = aw + bw;
    tx += __shfl_xor(tx, 32);
    ty += __shfl_xor(ty, 32);
    tz += __shfl_xor(tz, 32);
    tw += __shfl_xor(tw, 32);
    if (half == 0) {
        const float inv = 1.0f / fmaxf((float)(e - s), 1.0f);
        float4 o; o.x = tx * inv; o.y = ty * inv; o.z = tz * inv; o.w = tw * inv;
        *(float4*)(out + (size_t)w * H + fc) = o;
    }
}

// ------------------------------------------------------------ fused GEMM
// out[n x 128] = maybe_relu(0.5*(A1@W1 + A2@W2 + A3@W3 + bias))
#define GBM 64
#define GBK 32
__global__ __launch_bounds__(256)
void gemm3_k(int n,
             const float* __restrict__ A1, const float* __restrict__ W1,
             const float* __restrict__ A2, const float* __restrict__ W2,
             const float* __restrict__ A3, const float* __restrict__ W3,
             const float* __restrict__ bias, float* __restrict__ out, int relu) {
    __shared__ float Ast[GBK][GBM + 4];
    __shared__ float Ws[GBK][H];
    const int tid  = threadIdx.x;
    const int tx   = tid & 15;
    const int ty   = tid >> 4;
    const int row0 = blockIdx.x * GBM;

    float acc[4][8];
    #pragma unroll
    for (int i = 0; i < 4; ++i)
        #pragma unroll
        for (int j = 0; j < 8; ++j) acc[i][j] = 0.f;

    const float* Ap[3] = {A1, A2, A3};
    const float* Wp[3] = {W1, W2, W3};

    for (int term = 0; term < 3; ++term) {
        const float* A = Ap[term];
        const float* W = Wp[term];
        #pragma unroll 1
        for (int k0 = 0; k0 < H; k0 += GBK) {
            #pragma unroll
            for (int f = tid; f < GBM * GBK / 4; f += 256) {
                int r = f >> 3, c4 = f & 7;
                int gr = row0 + r;
                float4 v = (gr < n) ? *(const float4*)(A + (size_t)gr * H + k0 + c4 * 4)
                                    : make_float4(0.f, 0.f, 0.f, 0.f);
                Ast[c4 * 4 + 0][r] = v.x; Ast[c4 * 4 + 1][r] = v.y;
                Ast[c4 * 4 + 2][r] = v.z; Ast[c4 * 4 + 3][r] = v.w;
            }
            #pragma unroll
            for (int f = tid; f < GBK * H / 4; f += 256) {
                int r = f >> 5, c4 = f & 31;
                *(float4*)&Ws[r][c4 * 4] = *(const float4*)(W + (size_t)(k0 + r) * H + c4 * 4);
            }
            __syncthreads();
            #pragma unroll
            for (int kk = 0; kk < GBK; ++kk) {
                float4 av = *(const float4*)&Ast[kk][ty * 4];
                float4 w0 = *(const float4*)&Ws[kk][tx * 8];
                float4 w1 = *(const float4*)&Ws[kk][tx * 8 + 4];
                float a[4] = {av.x, av.y, av.z, av.w};
                float w[8] = {w0.x, w0.y, w0.z, w0.w, w1.x, w1.y, w1.z, w1.w};
                #pragma unroll
                for (int i = 0; i < 4; ++i)
                    #pragma unroll
                    for (int j = 0; j < 8; ++j)
                        acc[i][j] = fmaf(a[i], w[j], acc[i][j]);
            }
            __syncthreads();
        }
    }
    #pragma unroll
    for (int i = 0; i < 4; ++i) {
        int gr = row0 + ty * 4 + i;
        if (gr < n) {
            float* orow = out + (size_t)gr * H + tx * 8;
            #pragma unroll
            for (int j = 0; j < 8; ++j) {
                float v = 0.5f * (acc[i][j] + bias[tx * 8 + j]);
                if (relu) v = fmaxf(v, 0.f);
                orow[j] = v;
            }
        }
    }
}

// -------------------------------------------------------------- L2 norm
__global__ __launch_bounds__(256)
void norm_k(const float* __restrict__ h, float* __restrict__ out, int n) {
    int w    = (blockIdx.x * 256 + threadIdx.x) >> 6;
    int lane = threadIdx.x & 63;
    if (w >= n) return;
    const float2 v = *(const float2*)(h + (size_t)w * H + lane * 2);
    float ss = v.x * v.x + v.y * v.y;
    #pragma unroll
    for (int off = 32; off; off >>= 1) ss += __shfl_xor(ss, off);
    float scale = 1.0f / fmaxf(sqrtf(ss), 1e-12f);
    float2 o; o.x = v.x * scale; o.y = v.y * scale;
    *(float2*)(out + (size_t)w * H + lane * 2) = o;
}

// ---------------------------------------------------------------- launch
extern "C" void kernel_launch(void* const* d_in, const int* in_sizes, int n_in,
                              void* d_out, int out_size, void* d_ws, size_t ws_size,
                              hipStream_t stream) {
    const float* x[3] = {(const float*)d_in[0], (const float*)d_in[1], (const float*)d_in[2]};
    const int* srcp[6] = {(const int*)d_in[3], (const int*)d_in[5], (const int*)d_in[7],
                          (const int*)d_in[9], (const int*)d_in[11], (const int*)d_in[13]};
    const int* dstp[6] = {(const int*)d_in[4], (const int*)d_in[6], (const int*)d_in[8],
                          (const int*)d_in[10], (const int*)d_in[12], (const int*)d_in[14]};
    const float* Wl = (const float*)d_in[15];
    const float* Wr = (const float*)d_in[16];
    const float* b  = (const float*)d_in[17];
    float* outp = (float*)d_out;

    const int nNode[3]   = {NC_N, NM_N, ND_N};
    const int E[6]       = {800000, 400000, 800000, 800000, 400000, 800000};
    const int nDst[6]    = {NM_N, ND_N, ND_N, NC_N, NM_N, NC_N};
    const int srcType[6] = {0, 1, 0, 1, 2, 2};
    const int relA[3] = {3, 0, 1}, relB[3] = {5, 4, 2};

    // ---- workspace carve-up (256B aligned), total ~115.6 MB
    char* p = (char*)d_ws;
    auto alloc = [&](size_t bytes) -> char* {
        char* r = p; p += (bytes + 255) & ~(size_t)255; return r;
    };
    float* hbuf0 = (float*)alloc((size_t)NTOT * H * 4);
    float* aggA  = (float*)alloc((size_t)NC_N * H * 4);
    float* aggB  = (float*)alloc((size_t)NC_N * H * 4);
    float* Wsum  = (float*)alloc((size_t)4 * 3 * H * H * 4);
    float* bsum  = (float*)alloc((size_t)4 * 3 * H * 4);
    int*   cnt   = (int*)alloc((size_t)180000 * 4);
    int*   offs  = (int*)alloc((size_t)180006 * 4);
    int*   csr   = (int*)alloc((size_t)4000000 * 4);
    float* hbuf1 = outp;

    BuildArgs ba;
    { int ob = 0, cb = 0, nb = 0, bb = 0;
      for (int r = 0; r < 6; ++r) {
          ba.dstp[r] = dstp[r]; ba.srcp[r] = srcp[r];
          ba.E[r] = E[r]; ba.nDst[r] = nDst[r];
          ba.blockBase[r] = bb; bb += (E[r] + 255) / 256;
          ba.offsBase[r] = ob; ob += nDst[r] + 1;
          ba.csrBase[r]  = cb; cb += E[r];
          ba.cntBase[r]  = nb; nb += nDst[r];
      }
      ba.blockBase[6] = bb; }

    // ---- CSR build (once, reused by all layers)
    hipMemsetAsync(cnt, 0, 180000 * 4, stream);
    count_all_k<<<ba.blockBase[6], 256, 0, stream>>>(ba, cnt);
    scan_all_k<<<6, 1024, 0, stream>>>(ba, cnt, offs);
    hipMemsetAsync(cnt, 0, 180000 * 4, stream);          // reuse as fill cursors
    fill_all_k<<<ba.blockBase[6], 256, 0, stream>>>(ba, offs, cnt, csr);

    combine_k<<<(4 * 3 * H * H + 255) / 256, 256, 0, stream>>>(Wr, b, Wsum, bsum);

    const size_t tOff[3] = {0, (size_t)NC_N * H, (size_t)(NC_N + NM_N) * H};
    float* hb[2] = {hbuf0, hbuf1};

    int cur = -1, nxt = 0;
    for (int l = 0; l < 4; ++l) {
        float* dstBuf = hb[nxt];
        for (int t = 0; t < 3; ++t) {
            int rA = relA[t], rB = relB[t];
            const float* hsA = (l == 0) ? x[srcType[rA]] : hb[cur] + tOff[srcType[rA]];
            const float* hsB = (l == 0) ? x[srcType[rB]] : hb[cur] + tOff[srcType[rB]];
            const float* hT  = (l == 0) ? x[t]           : hb[cur] + tOff[t];
            int n = nNode[t];
            int halfBlocks = (n + 3) / 4;
            agg2_k<<<2 * halfBlocks, 256, 0, stream>>>(
                hsA, offs + ba.offsBase[rA], csr + ba.csrBase[rA],
                hsB, offs + ba.offsBase[rB], csr + ba.csrBase[rB],
                aggA, aggB, n, halfBlocks);
            gemm3_k<<<(n + GBM - 1) / GBM, 256, 0, stream>>>(
                n,
                aggA, Wl + (size_t)(l * 6 + rA) * H * H,
                aggB, Wl + (size_t)(l * 6 + rB) * H * H,
                hT,   Wsum + (size_t)(l * 3 + t) * H * H,
                bsum + (size_t)(l * 3 + t) * H,
                dstBuf + tOff[t], (l < 3) ? 1 : 0);
        }
        cur = nxt; nxt ^= 1;
    }
    norm_k<<<(NTOT + 3) / 4, 256, 0, stream>>>(hb[cur], outp, NTOT);
}

// Round 5
// 1384.826 us; speedup vs baseline: 2.4386x; 1.6006x over previous
//
#include <hip/hip_runtime.h>
#include <hip/hip_bf16.h>

// HeteroGraphSAGE on MI355X — round 4.
// Round-3 profile: fill_all_k 198us (scatter write-amp, deferred); agg+gemm ~1.8ms.
// Changes:
//   * h stored bf16: gather bytes halve; one wave covers a 256B row (1 dword/lane),
//     8 edges in flight.
//   * GEMM -> MFMA 16x16x32 bf16, fp32 accumulate. W transposed+bf16 once per call
//     (prep_w_k); A/B frags are contiguous ds_read_b128 from stride-80B LDS.
//   * Final layer writes fp32 directly to d_out; norm in place.

#define NC_N 50000
#define NM_N 30000
#define ND_N 10000
#define NTOT 90000
#define H    128

typedef __attribute__((ext_vector_type(8))) short short8;
typedef __attribute__((ext_vector_type(4))) float f32x4;

__device__ __forceinline__ ushort f2bf(float f) {
    uint u = __float_as_uint(f);
    return (ushort)((u + 0x7fffu + ((u >> 16) & 1u)) >> 16);   // RNE
}
__device__ __forceinline__ float bflo(uint v) { return __uint_as_float(v << 16); }
__device__ __forceinline__ float bfhi(uint v) { return __uint_as_float(v & 0xffff0000u); }

// ---------------------------------------------------------------- CSR build
struct BuildArgs {
    const int* dstp[6];
    const int* srcp[6];
    int blockBase[7];
    int E[6];
    int cntBase[6];
    int offsBase[6];
    int csrBase[6];
    int nDst[6];
};

__global__ void count_all_k(BuildArgs a, int* __restrict__ cnt) {
    int b = blockIdx.x, r = 0;
    #pragma unroll
    for (int k = 1; k <= 5; ++k) if (b >= a.blockBase[k]) r = k;
    int i = (b - a.blockBase[r]) * 256 + threadIdx.x;
    if (i < a.E[r]) atomicAdd(&cnt[a.cntBase[r] + a.dstp[r][i]], 1);
}

__global__ void scan_all_k(BuildArgs a, const int* __restrict__ cnt,
                           int* __restrict__ offsAll) {
    const int r = blockIdx.x;
    const int* c = cnt + a.cntBase[r];
    int* offs = offsAll + a.offsBase[r];
    const int n = a.nDst[r];
    __shared__ int buf[1024];
    __shared__ int s_carry;
    int tid = threadIdx.x;
    if (tid == 0) { s_carry = 0; offs[0] = 0; }
    __syncthreads();
    for (int base = 0; base < n; base += 1024) {
        int i = base + tid;
        int v = (i < n) ? c[i] : 0;
        buf[tid] = v;
        __syncthreads();
        #pragma unroll
        for (int off = 1; off < 1024; off <<= 1) {
            int t = (tid >= off) ? buf[tid - off] : 0;
            __syncthreads();
            buf[tid] += t;
            __syncthreads();
        }
        int incl = buf[tid] + s_carry;
        if (i < n) offs[i + 1] = incl;
        __syncthreads();
        if (tid == 0) s_carry += buf[1023];
        __syncthreads();
    }
}

__global__ void fill_all_k(BuildArgs a, const int* __restrict__ offs,
                           int* __restrict__ cur, int* __restrict__ csr) {
    int b = blockIdx.x, r = 0;
    #pragma unroll
    for (int k = 1; k <= 5; ++k) if (b >= a.blockBase[k]) r = k;
    int i = (b - a.blockBase[r]) * 256 + threadIdx.x;
    if (i < a.E[r]) {
        int d = a.dstp[r][i];
        int p = atomicAdd(&cur[a.cntBase[r] + d], 1);
        csr[a.csrBase[r] + offs[a.offsBase[r] + d] + p] = a.srcp[r][i];
    }
}

// ---------------------------------------------- weight prep: bf16 + transpose
// blk 0..23: WlT[blk] = transpose(Wl[blk]) as bf16
// blk 24..35: lt=blk-24: WsumT[lt] = transpose(Wr[l,rA]+Wr[l,rB]) bf16; bsum fp32
__global__ void prep_w_k(const float* __restrict__ Wl, const float* __restrict__ Wr,
                         const float* __restrict__ b,
                         ushort* __restrict__ WlT, ushort* __restrict__ WsumT,
                         float* __restrict__ bsum) {
    const int rA[3] = {3, 0, 1}, rB[3] = {5, 4, 2};
    int blk = blockIdx.x, tid = threadIdx.x;
    int nr = tid >> 1;
    int k0 = (tid & 1) * 64;
    if (blk < 24) {
        const float* src = Wl + (size_t)blk * 16384;
        ushort* dst = WlT + (size_t)blk * 16384;
        for (int k = k0; k < k0 + 64; ++k)
            dst[nr * 128 + k] = f2bf(src[k * 128 + nr]);
    } else {
        int lt = blk - 24, l = lt / 3, t = lt % 3;
        const float* sA = Wr + (size_t)(l * 6 + rA[t]) * 16384;
        const float* sB = Wr + (size_t)(l * 6 + rB[t]) * 16384;
        ushort* dst = WsumT + (size_t)lt * 16384;
        for (int k = k0; k < k0 + 64; ++k)
            dst[nr * 128 + k] = f2bf(sA[k * 128 + nr] + sB[k * 128 + nr]);
        if (tid < 128)
            bsum[lt * 128 + tid] = b[(l * 6 + rA[t]) * 128 + tid] +
                                   b[(l * 6 + rB[t]) * 128 + tid];
    }
}

// ------------------------------------------------------- x -> bf16 h0
__global__ void cvt_x_k(const float* __restrict__ xc, const float* __restrict__ xm,
                        const float* __restrict__ xd, ushort* __restrict__ h) {
    int i = blockIdx.x * 256 + threadIdx.x;
    const int tot = NTOT * H / 8;
    if (i >= tot) return;
    size_t base = (size_t)i * 8;
    int row = (int)(base >> 7);
    const float* src; size_t local;
    if (row < NC_N) { src = xc; local = base; }
    else if (row < NC_N + NM_N) { src = xm; local = base - (size_t)NC_N * H; }
    else { src = xd; local = base - (size_t)(NC_N + NM_N) * H; }
    float4 v0 = *(const float4*)(src + local);
    float4 v1 = *(const float4*)(src + local + 4);
    uint4 o;
    o.x = (uint)f2bf(v0.x) | ((uint)f2bf(v0.y) << 16);
    o.y = (uint)f2bf(v0.z) | ((uint)f2bf(v0.w) << 16);
    o.z = (uint)f2bf(v1.x) | ((uint)f2bf(v1.y) << 16);
    o.w = (uint)f2bf(v1.z) | ((uint)f2bf(v1.w) << 16);
    *(uint4*)(h + base) = o;
}

// ----------------------------------------------------------- segment mean
// bf16 rows (256B). One wave per dst node; lane holds 1 dword (2 features).
// 8 edges in flight per main iter.
__global__ __launch_bounds__(256)
void agg2b_k(const ushort* __restrict__ srcA, const int* __restrict__ offsA,
             const int* __restrict__ csrA,
             const ushort* __restrict__ srcB, const int* __restrict__ offsB,
             const int* __restrict__ csrB,
             ushort* __restrict__ outA, ushort* __restrict__ outB,
             int n, int halfBlocks) {
    const int b = blockIdx.x;
    const bool isB = (b >= halfBlocks);
    const uint* __restrict__ src = (const uint*)(isB ? srcB : srcA);
    const int* __restrict__ offs = isB ? offsB : offsA;
    const int* __restrict__ csr  = isB ? csrB : csrA;
    uint* __restrict__ out       = (uint*)(isB ? outB : outA);
    const int w = (b - (isB ? halfBlocks : 0)) * 4 + (int)(threadIdx.x >> 6);
    if (w >= n) return;
    const int lane = threadIdx.x & 63;
    const int s = offs[w], e = offs[w + 1];

    float a0 = 0.f, a1 = 0.f;
    int j = s;
    for (; j + 8 <= e; j += 8) {
        int i0 = csr[j + 0], i1 = csr[j + 1], i2 = csr[j + 2], i3 = csr[j + 3];
        int i4 = csr[j + 4], i5 = csr[j + 5], i6 = csr[j + 6], i7 = csr[j + 7];
        uint v0 = src[(size_t)i0 * 64 + lane];
        uint v1 = src[(size_t)i1 * 64 + lane];
        uint v2 = src[(size_t)i2 * 64 + lane];
        uint v3 = src[(size_t)i3 * 64 + lane];
        uint v4 = src[(size_t)i4 * 64 + lane];
        uint v5 = src[(size_t)i5 * 64 + lane];
        uint v6 = src[(size_t)i6 * 64 + lane];
        uint v7 = src[(size_t)i7 * 64 + lane];
        a0 += bflo(v0) + bflo(v1) + bflo(v2) + bflo(v3)
            + bflo(v4) + bflo(v5) + bflo(v6) + bflo(v7);
        a1 += bfhi(v0) + bfhi(v1) + bfhi(v2) + bfhi(v3)
            + bfhi(v4) + bfhi(v5) + bfhi(v6) + bfhi(v7);
    }
    for (; j + 4 <= e; j += 4) {
        int i0 = csr[j + 0], i1 = csr[j + 1], i2 = csr[j + 2], i3 = csr[j + 3];
        uint v0 = src[(size_t)i0 * 64 + lane];
        uint v1 = src[(size_t)i1 * 64 + lane];
        uint v2 = src[(size_t)i2 * 64 + lane];
        uint v3 = src[(size_t)i3 * 64 + lane];
        a0 += bflo(v0) + bflo(v1) + bflo(v2) + bflo(v3);
        a1 += bfhi(v0) + bfhi(v1) + bfhi(v2) + bfhi(v3);
    }
    for (; j < e; ++j) {
        uint v = src[(size_t)csr[j] * 64 + lane];
        a0 += bflo(v); a1 += bfhi(v);
    }
    const float inv = 1.0f / fmaxf((float)(e - s), 1.0f);
    out[(size_t)w * 64 + lane] = (uint)f2bf(a0 * inv) | ((uint)f2bf(a1 * inv) << 16);
}

// ------------------------------------------------------------ MFMA GEMM
// out[n x 128] = epi(0.5*(A1@W1 + A2@W2 + A3@W3 + bias))
// A*: [n][128] bf16 row-major. W*t: [128 n][128 k] bf16 (pre-transposed).
// Block: 256 thr / 4 waves; tile 128 rows; wave -> 32 rows; 16x16x32 MFMA.
// mode 0: relu -> bf16 out; mode 1: plain -> fp32 out.
__global__ __launch_bounds__(256)
void gemm3m_k(int n,
              const ushort* __restrict__ A1, const ushort* __restrict__ W1t,
              const ushort* __restrict__ A2, const ushort* __restrict__ W2t,
              const ushort* __restrict__ A3, const ushort* __restrict__ W3t,
              const float* __restrict__ bias, void* __restrict__ outv, int mode) {
    __shared__ ushort As[128][40];   // stride 80B: 16B-aligned, ~2-way banks
    __shared__ ushort Bs[128][40];
    const int tid  = threadIdx.x;
    const int wave = tid >> 6, lane = tid & 63;
    const int lr = lane & 15, lk = lane >> 4;
    const int row0 = blockIdx.x * 128;

    f32x4 acc[2][8];
    #pragma unroll
    for (int i = 0; i < 2; ++i)
        #pragma unroll
        for (int j = 0; j < 8; ++j) acc[i][j] = (f32x4)0.f;

    const ushort* Ap[3] = {A1, A2, A3};
    const ushort* Wp[3] = {W1t, W2t, W3t};

    const int rs = tid >> 2;          // staging row 0..63 (+64 on pass 2)
    const int kb = (tid & 3) * 8;     // staging k-offset (bf16 units)

    for (int term = 0; term < 3; ++term) {
        const ushort* A = Ap[term];
        const ushort* W = Wp[term];
        #pragma unroll 1
        for (int k0 = 0; k0 < 128; k0 += 32) {
            #pragma unroll
            for (int p = 0; p < 2; ++p) {
                int rr = rs + p * 64;
                int gr = row0 + rr;
                short8 av = (short8)0;
                if (gr < n) av = *(const short8*)(A + (size_t)gr * 128 + k0 + kb);
                *(short8*)&As[rr][kb] = av;
                short8 wv = *(const short8*)(W + (size_t)rr * 128 + k0 + kb);
                *(short8*)&Bs[rr][kb] = wv;
            }
            __syncthreads();
            short8 af0 = *(const short8*)&As[wave * 32 + lr][lk * 8];
            short8 af1 = *(const short8*)&As[wave * 32 + 16 + lr][lk * 8];
            #pragma unroll
            for (int nt = 0; nt < 8; ++nt) {
                short8 bf = *(const short8*)&Bs[nt * 16 + lr][lk * 8];
                acc[0][nt] = __builtin_amdgcn_mfma_f32_16x16x32_bf16(af0, bf, acc[0][nt], 0, 0, 0);
                acc[1][nt] = __builtin_amdgcn_mfma_f32_16x16x32_bf16(af1, bf, acc[1][nt], 0, 0, 0);
            }
            __syncthreads();
        }
    }
    // epilogue: D frag mapping col=lane&15, row=(lane>>4)*4+r  [verified m89]
    #pragma unroll
    for (int mt = 0; mt < 2; ++mt) {
        #pragma unroll
        for (int nt = 0; nt < 8; ++nt) {
            int col = nt * 16 + lr;
            float bv = bias[col];
            #pragma unroll
            for (int r = 0; r < 4; ++r) {
                int row = row0 + wave * 32 + mt * 16 + lk * 4 + r;
                if (row < n) {
                    float v = 0.5f * (acc[mt][nt][r] + bv);
                    if (mode == 0) {
                        v = fmaxf(v, 0.f);
                        ((ushort*)outv)[(size_t)row * 128 + col] = f2bf(v);
                    } else {
                        ((float*)outv)[(size_t)row * 128 + col] = v;
                    }
                }
            }
        }
    }
}

// -------------------------------------------------------------- L2 norm
__global__ __launch_bounds__(256)
void norm_k(const float* __restrict__ h, float* __restrict__ out, int n) {
    int w    = (blockIdx.x * 256 + threadIdx.x) >> 6;
    int lane = threadIdx.x & 63;
    if (w >= n) return;
    const float2 v = *(const float2*)(h + (size_t)w * H + lane * 2);
    float ss = v.x * v.x + v.y * v.y;
    #pragma unroll
    for (int off = 32; off; off >>= 1) ss += __shfl_xor(ss, off);
    float scale = 1.0f / fmaxf(sqrtf(ss), 1e-12f);
    float2 o; o.x = v.x * scale; o.y = v.y * scale;
    *(float2*)(out + (size_t)w * H + lane * 2) = o;
}

// ---------------------------------------------------------------- launch
extern "C" void kernel_launch(void* const* d_in, const int* in_sizes, int n_in,
                              void* d_out, int out_size, void* d_ws, size_t ws_size,
                              hipStream_t stream) {
    const float* x[3] = {(const float*)d_in[0], (const float*)d_in[1], (const float*)d_in[2]};
    const int* srcp[6] = {(const int*)d_in[3], (const int*)d_in[5], (const int*)d_in[7],
                          (const int*)d_in[9], (const int*)d_in[11], (const int*)d_in[13]};
    const int* dstp[6] = {(const int*)d_in[4], (const int*)d_in[6], (const int*)d_in[8],
                          (const int*)d_in[10], (const int*)d_in[12], (const int*)d_in[14]};
    const float* Wl = (const float*)d_in[15];
    const float* Wr = (const float*)d_in[16];
    const float* b  = (const float*)d_in[17];
    float* outp = (float*)d_out;

    const int nNode[3]   = {NC_N, NM_N, ND_N};
    const int E[6]       = {800000, 400000, 800000, 800000, 400000, 800000};
    const int nDst[6]    = {NM_N, ND_N, ND_N, NC_N, NM_N, NC_N};
    const int srcType[6] = {0, 1, 0, 1, 2, 2};
    const int relA[3] = {3, 0, 1}, relB[3] = {5, 4, 2};

    // ---- workspace carve-up (256B aligned), total ~91 MB
    char* p = (char*)d_ws;
    auto alloc = [&](size_t bytes) -> char* {
        char* r = p; p += (bytes + 255) & ~(size_t)255; return r;
    };
    ushort* hA    = (ushort*)alloc((size_t)NTOT * H * 2);
    ushort* hB    = (ushort*)alloc((size_t)NTOT * H * 2);
    ushort* aggA  = (ushort*)alloc((size_t)NC_N * H * 2);
    ushort* aggB  = (ushort*)alloc((size_t)NC_N * H * 2);
    ushort* WlT   = (ushort*)alloc((size_t)24 * H * H * 2);
    ushort* WsumT = (ushort*)alloc((size_t)12 * H * H * 2);
    float*  bsum  = (float*)alloc((size_t)12 * H * 4);
    int*    cnt   = (int*)alloc((size_t)180000 * 4);
    int*    offs  = (int*)alloc((size_t)180006 * 4);
    int*    csr   = (int*)alloc((size_t)4000000 * 4);

    BuildArgs ba;
    { int ob = 0, cb = 0, nb = 0, bb = 0;
      for (int r = 0; r < 6; ++r) {
          ba.dstp[r] = dstp[r]; ba.srcp[r] = srcp[r];
          ba.E[r] = E[r]; ba.nDst[r] = nDst[r];
          ba.blockBase[r] = bb; bb += (E[r] + 255) / 256;
          ba.offsBase[r] = ob; ob += nDst[r] + 1;
          ba.csrBase[r]  = cb; cb += E[r];
          ba.cntBase[r]  = nb; nb += nDst[r];
      }
      ba.blockBase[6] = bb; }

    // ---- CSR build (once, reused by all layers)
    hipMemsetAsync(cnt, 0, 180000 * 4, stream);
    count_all_k<<<ba.blockBase[6], 256, 0, stream>>>(ba, cnt);
    scan_all_k<<<6, 1024, 0, stream>>>(ba, cnt, offs);
    hipMemsetAsync(cnt, 0, 180000 * 4, stream);
    fill_all_k<<<ba.blockBase[6], 256, 0, stream>>>(ba, offs, cnt, csr);

    prep_w_k<<<36, 256, 0, stream>>>(Wl, Wr, b, WlT, WsumT, bsum);
    cvt_x_k<<<(NTOT * H / 8 + 255) / 256, 256, 0, stream>>>(x[0], x[1], x[2], hA);

    const size_t tOff[3] = {0, (size_t)NC_N * H, (size_t)(NC_N + NM_N) * H};
    ushort* hb[2] = {hA, hB};

    int cur = 0;
    for (int l = 0; l < 4; ++l) {
        ushort* hsrc = hb[cur];
        ushort* hdst = hb[cur ^ 1];
        for (int t = 0; t < 3; ++t) {
            int rA = relA[t], rB = relB[t];
            int n = nNode[t];
            int halfBlocks = (n + 3) / 4;
            agg2b_k<<<2 * halfBlocks, 256, 0, stream>>>(
                hsrc + tOff[srcType[rA]], offs + ba.offsBase[rA], csr + ba.csrBase[rA],
                hsrc + tOff[srcType[rB]], offs + ba.offsBase[rB], csr + ba.csrBase[rB],
                aggA, aggB, n, halfBlocks);
            void* outPtr = (l < 3) ? (void*)(hdst + tOff[t])
                                   : (void*)(outp + tOff[t]);
            gemm3m_k<<<(n + 127) / 128, 256, 0, stream>>>(
                n,
                aggA, WlT + (size_t)(l * 6 + rA) * H * H,
                aggB, WlT + (size_t)(l * 6 + rB) * H * H,
                hsrc + tOff[t], WsumT + (size_t)(l * 3 + t) * H * H,
                bsum + (size_t)(l * 3 + t) * H,
                outPtr, (l < 3) ? 0 : 1);
        }
        cur ^= 1;
    }
    norm_k<<<(NTOT + 3) / 4, 256, 0, stream>>>(outp, outp, NTOT);
}

// Round 6
// 1317.215 us; speedup vs baseline: 2.5638x; 1.0513x over previous
//
#include <hip/hip_runtime.h>
#include <hip/hip_bf16.h>

// HeteroGraphSAGE on MI355X — round 5.
// Round-4 profile: fill_all_k 210us, WRITE_SIZE 254MB vs 16MB csr = 16x write
// amplification (cross-XCD line ping-pong on random 4B scatter).
// Changes:
//   * Binned two-phase CSR fill: phase A scatters (src,dst) pairs bin-ordered
//     (bin = dst-range; per-block LDS hist + one cursor bump per (block,bin);
//     bin offsets come free from node-level offs). Phase B: one block per bin
//     places edges into a contiguous csr region via LDS per-dst cursors.
//     Staging aliases hA/hB (used before cvt_x writes them).
//   * agg2b v2: uint2/lane (half-row), 2 edges per load, 16 edges in flight.
//   * gemm3m/prep/cvt/norm unchanged.

#define NC_N 50000
#define NM_N 30000
#define ND_N 10000
#define NTOT 90000
#define H    128

typedef __attribute__((ext_vector_type(8))) short short8;
typedef __attribute__((ext_vector_type(4))) float f32x4;

__device__ __forceinline__ ushort f2bf(float f) {
    uint u = __float_as_uint(f);
    return (ushort)((u + 0x7fffu + ((u >> 16) & 1u)) >> 16);   // RNE
}
__device__ __forceinline__ float bflo(uint v) { return __uint_as_float(v << 16); }
__device__ __forceinline__ float bfhi(uint v) { return __uint_as_float(v & 0xffff0000u); }

// ---------------------------------------------------------------- CSR build
#define ACHUNK 2048   // edges per phase-A block

struct BuildArgs {
    const int* dstp[6];
    const int* srcp[6];
    int blockBase[7];    // prefix over ceil(E/256)   (count kernel)
    int ablockBase[7];   // prefix over ceil(E/ACHUNK) (phase A)
    int binBase[7];      // prefix over nBins
    int E[6];
    int cntBase[6];
    int offsBase[6];
    int csrBase[6];
    int nDst[6];
    int shift[6];
};

__global__ void count_all_k(BuildArgs a, int* __restrict__ cnt) {
    int b = blockIdx.x, r = 0;
    #pragma unroll
    for (int k = 1; k <= 5; ++k) if (b >= a.blockBase[k]) r = k;
    int i = (b - a.blockBase[r]) * 256 + threadIdx.x;
    if (i < a.E[r]) atomicAdd(&cnt[a.cntBase[r] + a.dstp[r][i]], 1);
}

__global__ void scan_all_k(BuildArgs a, const int* __restrict__ cnt,
                           int* __restrict__ offsAll) {
    const int r = blockIdx.x;
    const int* c = cnt + a.cntBase[r];
    int* offs = offsAll + a.offsBase[r];
    const int n = a.nDst[r];
    __shared__ int buf[1024];
    __shared__ int s_carry;
    int tid = threadIdx.x;
    if (tid == 0) { s_carry = 0; offs[0] = 0; }
    __syncthreads();
    for (int base = 0; base < n; base += 1024) {
        int i = base + tid;
        int v = (i < n) ? c[i] : 0;
        buf[tid] = v;
        __syncthreads();
        #pragma unroll
        for (int off = 1; off < 1024; off <<= 1) {
            int t = (tid >= off) ? buf[tid - off] : 0;
            __syncthreads();
            buf[tid] += t;
            __syncthreads();
        }
        int incl = buf[tid] + s_carry;
        if (i < n) offs[i + 1] = incl;
        __syncthreads();
        if (tid == 0) s_carry += buf[1023];
        __syncthreads();
    }
}

// bin cursors init: binCur[g] = csrBase[r] + offs[offsBase[r] + (b<<shift)]
__global__ void initbins_k(BuildArgs a, const int* __restrict__ offs,
                           int* __restrict__ binCur, int totBins) {
    int g = blockIdx.x * 256 + threadIdx.x;
    if (g >= totBins) return;
    int r = 0;
    #pragma unroll
    for (int k = 1; k <= 5; ++k) if (g >= a.binBase[k]) r = k;
    int b = g - a.binBase[r];
    binCur[g] = a.csrBase[r] + offs[a.offsBase[r] + (b << a.shift[r])];
}

// phase A: scatter (src,dst) pairs into bin-ordered staging
__global__ __launch_bounds__(256)
void binscat_k(BuildArgs a, int* __restrict__ binCur, int2* __restrict__ staging) {
    __shared__ int hist[128], hbase[128], hcur[128];
    int blk = blockIdx.x, r = 0;
    #pragma unroll
    for (int k = 1; k <= 5; ++k) if (blk >= a.ablockBase[k]) r = k;
    const int i0 = (blk - a.ablockBase[r]) * ACHUNK;
    const int E = a.E[r], sh = a.shift[r];
    const int tid = threadIdx.x;
    if (tid < 128) { hist[tid] = 0; hcur[tid] = 0; }
    __syncthreads();
    int d[8], s[8], bn[8];
    bool ok[8];
    #pragma unroll
    for (int k = 0; k < 8; ++k) {
        int i = i0 + k * 256 + tid;
        ok[k] = (i < E);
        if (ok[k]) {
            d[k] = a.dstp[r][i];
            s[k] = a.srcp[r][i];
            bn[k] = d[k] >> sh;
            atomicAdd(&hist[bn[k]], 1);
        }
    }
    __syncthreads();
    if (tid < 128 && hist[tid] > 0)
        hbase[tid] = atomicAdd(&binCur[a.binBase[r] + tid], hist[tid]);
    __syncthreads();
    #pragma unroll
    for (int k = 0; k < 8; ++k) {
        if (ok[k]) {
            int lr = atomicAdd(&hcur[bn[k]], 1);
            staging[hbase[bn[k]] + lr] = make_int2(s[k], d[k]);
        }
    }
}

// phase B: one block per bin; place edges into contiguous csr region
__global__ __launch_bounds__(256)
void binplace_k(BuildArgs a, const int* __restrict__ offs,
                const int2* __restrict__ staging, int* __restrict__ csr) {
    __shared__ int cur[512];
    int g = blockIdx.x, r = 0;
    #pragma unroll
    for (int k = 1; k <= 5; ++k) if (g >= a.binBase[k]) r = k;
    const int b = g - a.binBase[r];
    const int sh = a.shift[r];
    const int dlo = b << sh;
    const int dhi = min(dlo + (1 << sh), a.nDst[r]);
    const int tid = threadIdx.x;
    for (int i = tid; i < dhi - dlo; i += 256)
        cur[i] = offs[a.offsBase[r] + dlo + i];
    __syncthreads();
    const int eLo = offs[a.offsBase[r] + dlo];
    const int eHi = offs[a.offsBase[r] + dhi];
    const int base = a.csrBase[r];
    for (int i = eLo + tid; i < eHi; i += 256) {
        int2 p = staging[base + i];
        int pos = atomicAdd(&cur[p.y - dlo], 1);
        csr[base + pos] = p.x;
    }
}

// ---------------------------------------------- weight prep: bf16 + transpose
__global__ void prep_w_k(const float* __restrict__ Wl, const float* __restrict__ Wr,
                         const float* __restrict__ b,
                         ushort* __restrict__ WlT, ushort* __restrict__ WsumT,
                         float* __restrict__ bsum) {
    const int rA[3] = {3, 0, 1}, rB[3] = {5, 4, 2};
    int blk = blockIdx.x, tid = threadIdx.x;
    int nr = tid >> 1;
    int k0 = (tid & 1) * 64;
    if (blk < 24) {
        const float* src = Wl + (size_t)blk * 16384;
        ushort* dst = WlT + (size_t)blk * 16384;
        for (int k = k0; k < k0 + 64; ++k)
            dst[nr * 128 + k] = f2bf(src[k * 128 + nr]);
    } else {
        int lt = blk - 24, l = lt / 3, t = lt % 3;
        const float* sA = Wr + (size_t)(l * 6 + rA[t]) * 16384;
        const float* sB = Wr + (size_t)(l * 6 + rB[t]) * 16384;
        ushort* dst = WsumT + (size_t)lt * 16384;
        for (int k = k0; k < k0 + 64; ++k)
            dst[nr * 128 + k] = f2bf(sA[k * 128 + nr] + sB[k * 128 + nr]);
        if (tid < 128)
            bsum[lt * 128 + tid] = b[(l * 6 + rA[t]) * 128 + tid] +
                                   b[(l * 6 + rB[t]) * 128 + tid];
    }
}

// ------------------------------------------------------- x -> bf16 h0
__global__ void cvt_x_k(const float* __restrict__ xc, const float* __restrict__ xm,
                        const float* __restrict__ xd, ushort* __restrict__ h) {
    int i = blockIdx.x * 256 + threadIdx.x;
    const int tot = NTOT * H / 8;
    if (i >= tot) return;
    size_t base = (size_t)i * 8;
    int row = (int)(base >> 7);
    const float* src; size_t local;
    if (row < NC_N) { src = xc; local = base; }
    else if (row < NC_N + NM_N) { src = xm; local = base - (size_t)NC_N * H; }
    else { src = xd; local = base - (size_t)(NC_N + NM_N) * H; }
    float4 v0 = *(const float4*)(src + local);
    float4 v1 = *(const float4*)(src + local + 4);
    uint4 o;
    o.x = (uint)f2bf(v0.x) | ((uint)f2bf(v0.y) << 16);
    o.y = (uint)f2bf(v0.z) | ((uint)f2bf(v0.w) << 16);
    o.z = (uint)f2bf(v1.x) | ((uint)f2bf(v1.y) << 16);
    o.w = (uint)f2bf(v1.z) | ((uint)f2bf(v1.w) << 16);
    *(uint4*)(h + base) = o;
}

// ----------------------------------------------------------- segment mean
// bf16 rows (256B = 32 uint2). Lanes 0..31 = even edge, lanes 32..63 = odd edge;
// each lane holds uint2 (4 feats). 8 loads/iter = 16 edges in flight.
__global__ __launch_bounds__(256)
void agg2b_k(const ushort* __restrict__ srcA, const int* __restrict__ offsA,
             const int* __restrict__ csrA,
             const ushort* __restrict__ srcB, const int* __restrict__ offsB,
             const int* __restrict__ csrB,
             ushort* __restrict__ outA, ushort* __restrict__ outB,
             int n, int halfBlocks) {
    const int b = blockIdx.x;
    const bool isB = (b >= halfBlocks);
    const uint2* __restrict__ src = (const uint2*)(isB ? srcB : srcA);
    const int* __restrict__ offs  = isB ? offsB : offsA;
    const int* __restrict__ csr   = isB ? csrB : csrA;
    uint2* __restrict__ out       = (uint2*)(isB ? outB : outA);
    const int w = (b - (isB ? halfBlocks : 0)) * 4 + (int)(threadIdx.x >> 6);
    if (w >= n) return;
    const int lane = threadIdx.x & 63;
    const int half = lane >> 5;
    const int lh   = lane & 31;
    const int s = offs[w], e = offs[w + 1];

    float a0 = 0.f, a1 = 0.f, a2 = 0.f, a3 = 0.f;
    int j = s;
    for (; j + 16 <= e; j += 16) {
        int i0 = csr[j + 0  + half], i1 = csr[j + 2  + half];
        int i2 = csr[j + 4  + half], i3 = csr[j + 6  + half];
        int i4 = csr[j + 8  + half], i5 = csr[j + 10 + half];
        int i6 = csr[j + 12 + half], i7 = csr[j + 14 + half];
        uint2 v0 = src[(size_t)i0 * 32 + lh];
        uint2 v1 = src[(size_t)i1 * 32 + lh];
        uint2 v2 = src[(size_t)i2 * 32 + lh];
        uint2 v3 = src[(size_t)i3 * 32 + lh];
        uint2 v4 = src[(size_t)i4 * 32 + lh];
        uint2 v5 = src[(size_t)i5 * 32 + lh];
        uint2 v6 = src[(size_t)i6 * 32 + lh];
        uint2 v7 = src[(size_t)i7 * 32 + lh];
        a0 += bflo(v0.x) + bflo(v1.x) + bflo(v2.x) + bflo(v3.x)
            + bflo(v4.x) + bflo(v5.x) + bflo(v6.x) + bflo(v7.x);
        a1 += bfhi(v0.x) + bfhi(v1.x) + bfhi(v2.x) + bfhi(v3.x)
            + bfhi(v4.x) + bfhi(v5.x) + bfhi(v6.x) + bfhi(v7.x);
        a2 += bflo(v0.y) + bflo(v1.y) + bflo(v2.y) + bflo(v3.y)
            + bflo(v4.y) + bflo(v5.y) + bflo(v6.y) + bflo(v7.y);
        a3 += bfhi(v0.y) + bfhi(v1.y) + bfhi(v2.y) + bfhi(v3.y)
            + bfhi(v4.y) + bfhi(v5.y) + bfhi(v6.y) + bfhi(v7.y);
    }
    for (; j + 2 <= e; j += 2) {
        int i0 = csr[j + half];
        uint2 v = src[(size_t)i0 * 32 + lh];
        a0 += bflo(v.x); a1 += bfhi(v.x); a2 += bflo(v.y); a3 += bfhi(v.y);
    }
    if (j < e && half == 0) {
        int i0 = csr[j];
        uint2 v = src[(size_t)i0 * 32 + lh];
        a0 += bflo(v.x); a1 += bfhi(v.x); a2 += bflo(v.y); a3 += bfhi(v.y);
    }
    a0 += __shfl_xor(a0, 32);
    a1 += __shfl_xor(a1, 32);
    a2 += __shfl_xor(a2, 32);
    a3 += __shfl_xor(a3, 32);
    if (half == 0) {
        const float inv = 1.0f / fmaxf((float)(e - s), 1.0f);
        uint2 o;
        o.x = (uint)f2bf(a0 * inv) | ((uint)f2bf(a1 * inv) << 16);
        o.y = (uint)f2bf(a2 * inv) | ((uint)f2bf(a3 * inv) << 16);
        out[(size_t)w * 32 + lh] = o;
    }
}

// ------------------------------------------------------------ MFMA GEMM
__global__ __launch_bounds__(256)
void gemm3m_k(int n,
              const ushort* __restrict__ A1, const ushort* __restrict__ W1t,
              const ushort* __restrict__ A2, const ushort* __restrict__ W2t,
              const ushort* __restrict__ A3, const ushort* __restrict__ W3t,
              const float* __restrict__ bias, void* __restrict__ outv, int mode) {
    __shared__ ushort As[128][40];
    __shared__ ushort Bs[128][40];
    const int tid  = threadIdx.x;
    const int wave = tid >> 6, lane = tid & 63;
    const int lr = lane & 15, lk = lane >> 4;
    const int row0 = blockIdx.x * 128;

    f32x4 acc[2][8];
    #pragma unroll
    for (int i = 0; i < 2; ++i)
        #pragma unroll
        for (int j = 0; j < 8; ++j) acc[i][j] = (f32x4)0.f;

    const ushort* Ap[3] = {A1, A2, A3};
    const ushort* Wp[3] = {W1t, W2t, W3t};

    const int rs = tid >> 2;
    const int kb = (tid & 3) * 8;

    for (int term = 0; term < 3; ++term) {
        const ushort* A = Ap[term];
        const ushort* W = Wp[term];
        #pragma unroll 1
        for (int k0 = 0; k0 < 128; k0 += 32) {
            #pragma unroll
            for (int p = 0; p < 2; ++p) {
                int rr = rs + p * 64;
                int gr = row0 + rr;
                short8 av = (short8)0;
                if (gr < n) av = *(const short8*)(A + (size_t)gr * 128 + k0 + kb);
                *(short8*)&As[rr][kb] = av;
                short8 wv = *(const short8*)(W + (size_t)rr * 128 + k0 + kb);
                *(short8*)&Bs[rr][kb] = wv;
            }
            __syncthreads();
            short8 af0 = *(const short8*)&As[wave * 32 + lr][lk * 8];
            short8 af1 = *(const short8*)&As[wave * 32 + 16 + lr][lk * 8];
            #pragma unroll
            for (int nt = 0; nt < 8; ++nt) {
                short8 bf = *(const short8*)&Bs[nt * 16 + lr][lk * 8];
                acc[0][nt] = __builtin_amdgcn_mfma_f32_16x16x32_bf16(af0, bf, acc[0][nt], 0, 0, 0);
                acc[1][nt] = __builtin_amdgcn_mfma_f32_16x16x32_bf16(af1, bf, acc[1][nt], 0, 0, 0);
            }
            __syncthreads();
        }
    }
    #pragma unroll
    for (int mt = 0; mt < 2; ++mt) {
        #pragma unroll
        for (int nt = 0; nt < 8; ++nt) {
            int col = nt * 16 + lr;
            float bv = bias[col];
            #pragma unroll
            for (int r = 0; r < 4; ++r) {
                int row = row0 + wave * 32 + mt * 16 + lk * 4 + r;
                if (row < n) {
                    float v = 0.5f * (acc[mt][nt][r] + bv);
                    if (mode == 0) {
                        v = fmaxf(v, 0.f);
                        ((ushort*)outv)[(size_t)row * 128 + col] = f2bf(v);
                    } else {
                        ((float*)outv)[(size_t)row * 128 + col] = v;
                    }
                }
            }
        }
    }
}

// -------------------------------------------------------------- L2 norm
__global__ __launch_bounds__(256)
void norm_k(const float* __restrict__ h, float* __restrict__ out, int n) {
    int w    = (blockIdx.x * 256 + threadIdx.x) >> 6;
    int lane = threadIdx.x & 63;
    if (w >= n) return;
    const float2 v = *(const float2*)(h + (size_t)w * H + lane * 2);
    float ss = v.x * v.x + v.y * v.y;
    #pragma unroll
    for (int off = 32; off; off >>= 1) ss += __shfl_xor(ss, off);
    float scale = 1.0f / fmaxf(sqrtf(ss), 1e-12f);
    float2 o; o.x = v.x * scale; o.y = v.y * scale;
    *(float2*)(out + (size_t)w * H + lane * 2) = o;
}

// ---------------------------------------------------------------- launch
extern "C" void kernel_launch(void* const* d_in, const int* in_sizes, int n_in,
                              void* d_out, int out_size, void* d_ws, size_t ws_size,
                              hipStream_t stream) {
    const float* x[3] = {(const float*)d_in[0], (const float*)d_in[1], (const float*)d_in[2]};
    const int* srcp[6] = {(const int*)d_in[3], (const int*)d_in[5], (const int*)d_in[7],
                          (const int*)d_in[9], (const int*)d_in[11], (const int*)d_in[13]};
    const int* dstp[6] = {(const int*)d_in[4], (const int*)d_in[6], (const int*)d_in[8],
                          (const int*)d_in[10], (const int*)d_in[12], (const int*)d_in[14]};
    const float* Wl = (const float*)d_in[15];
    const float* Wr = (const float*)d_in[16];
    const float* b  = (const float*)d_in[17];
    float* outp = (float*)d_out;

    const int nNode[3]   = {NC_N, NM_N, ND_N};
    const int E[6]       = {800000, 400000, 800000, 800000, 400000, 800000};
    const int nDst[6]    = {NM_N, ND_N, ND_N, NC_N, NM_N, NC_N};
    const int shiftR[6]  = {8, 7, 7, 9, 8, 9};   // ~128-512 dst nodes per bin
    const int srcType[6] = {0, 1, 0, 1, 2, 2};
    const int relA[3] = {3, 0, 1}, relB[3] = {5, 4, 2};

    // ---- workspace carve-up (256B aligned)
    char* p = (char*)d_ws;
    auto alloc = [&](size_t bytes) -> char* {
        char* r = p; p += (bytes + 255) & ~(size_t)255; return r;
    };
    ushort* hA    = (ushort*)alloc((size_t)NTOT * H * 2);
    ushort* hB    = (ushort*)alloc((size_t)NTOT * H * 2);
    ushort* aggA  = (ushort*)alloc((size_t)NC_N * H * 2);
    ushort* aggB  = (ushort*)alloc((size_t)NC_N * H * 2);
    ushort* WlT   = (ushort*)alloc((size_t)24 * H * H * 2);
    ushort* WsumT = (ushort*)alloc((size_t)12 * H * H * 2);
    float*  bsum  = (float*)alloc((size_t)12 * H * 4);
    int*    cnt   = (int*)alloc((size_t)180000 * 4);
    int*    offs  = (int*)alloc((size_t)180006 * 4);
    int*    csr   = (int*)alloc((size_t)4000000 * 4);
    int*    binCur= (int*)alloc((size_t)1024 * 4);
    // staging (32MB) aliases hA+hB (46MB) — consumed before cvt_x writes hA
    int2*   staging = (int2*)hA;

    BuildArgs ba;
    int totBins = 0;
    { int ob = 0, cb = 0, nb = 0, bb = 0, ab = 0, gb = 0;
      for (int r = 0; r < 6; ++r) {
          ba.dstp[r] = dstp[r]; ba.srcp[r] = srcp[r];
          ba.E[r] = E[r]; ba.nDst[r] = nDst[r]; ba.shift[r] = shiftR[r];
          ba.blockBase[r]  = bb; bb += (E[r] + 255) / 256;
          ba.ablockBase[r] = ab; ab += (E[r] + ACHUNK - 1) / ACHUNK;
          ba.binBase[r]    = gb; gb += (nDst[r] + (1 << shiftR[r]) - 1) >> shiftR[r];
          ba.offsBase[r] = ob; ob += nDst[r] + 1;
          ba.csrBase[r]  = cb; cb += E[r];
          ba.cntBase[r]  = nb; nb += nDst[r];
      }
      ba.blockBase[6] = bb; ba.ablockBase[6] = ab; ba.binBase[6] = gb;
      totBins = gb; }

    // ---- CSR build (once, reused by all layers)
    hipMemsetAsync(cnt, 0, 180000 * 4, stream);
    count_all_k<<<ba.blockBase[6], 256, 0, stream>>>(ba, cnt);
    scan_all_k<<<6, 1024, 0, stream>>>(ba, cnt, offs);
    initbins_k<<<(totBins + 255) / 256, 256, 0, stream>>>(ba, offs, binCur, totBins);
    binscat_k<<<ba.ablockBase[6], 256, 0, stream>>>(ba, binCur, staging);
    binplace_k<<<totBins, 256, 0, stream>>>(ba, offs, staging, csr);

    prep_w_k<<<36, 256, 0, stream>>>(Wl, Wr, b, WlT, WsumT, bsum);
    cvt_x_k<<<(NTOT * H / 8 + 255) / 256, 256, 0, stream>>>(x[0], x[1], x[2], hA);

    const size_t tOff[3] = {0, (size_t)NC_N * H, (size_t)(NC_N + NM_N) * H};
    ushort* hb[2] = {hA, hB};

    int cur = 0;
    for (int l = 0; l < 4; ++l) {
        ushort* hsrc = hb[cur];
        ushort* hdst = hb[cur ^ 1];
        for (int t = 0; t < 3; ++t) {
            int rA = relA[t], rB = relB[t];
            int n = nNode[t];
            int halfBlocks = (n + 3) / 4;
            agg2b_k<<<2 * halfBlocks, 256, 0, stream>>>(
                hsrc + tOff[srcType[rA]], offs + ba.offsBase[rA], csr + ba.csrBase[rA],
                hsrc + tOff[srcType[rB]], offs + ba.offsBase[rB], csr + ba.csrBase[rB],
                aggA, aggB, n, halfBlocks);
            void* outPtr = (l < 3) ? (void*)(hdst + tOff[t])
                                   : (void*)(outp + tOff[t]);
            gemm3m_k<<<(n + 127) / 128, 256, 0, stream>>>(
                n,
                aggA, WlT + (size_t)(l * 6 + rA) * H * H,
                aggB, WlT + (size_t)(l * 6 + rB) * H * H,
                hsrc + tOff[t], WsumT + (size_t)(l * 3 + t) * H * H,
                bsum + (size_t)(l * 3 + t) * H,
                outPtr, (l < 3) ? 0 : 1);
        }
        cur ^= 1;
    }
    norm_k<<<(NTOT + 3) / 4, 256, 0, stream>>>(outp, outp, NTOT);
}

// Round 7
// 876.985 us; speedup vs baseline: 3.8508x; 1.5020x over previous
//
#include <hip/hip_runtime.h>
#include <hip/hip_bf16.h>

// HeteroGraphSAGE on MI355X — round 6.
// Round-5 profile: count_all_k 182us, WRITE_SIZE 124MB vs 0.7MB cnt = cross-XCD
// atomic line ping-pong. Node-level count/scan eliminated: bin-level LDS-hist
// count + 1-block bin scan; binplace computes node offsets locally in LDS and
// writes offs coalesced. Also: per-layer merged agg (1 dispatch) and merged
// gemm (1 dispatch); final L2-norm fused into last gemm epilogue.

#define NC_N 50000
#define NM_N 30000
#define ND_N 10000
#define NTOT 90000
#define H    128

typedef __attribute__((ext_vector_type(8))) short short8;
typedef __attribute__((ext_vector_type(4))) float f32x4;

__device__ __forceinline__ ushort f2bf(float f) {
    uint u = __float_as_uint(f);
    return (ushort)((u + 0x7fffu + ((u >> 16) & 1u)) >> 16);   // RNE
}
__device__ __forceinline__ float bflo(uint v) { return __uint_as_float(v << 16); }
__device__ __forceinline__ float bfhi(uint v) { return __uint_as_float(v & 0xffff0000u); }

// ---------------------------------------------------------------- CSR build
#define ACHUNK 2048   // edges per phase-A block

struct BuildArgs {
    const int* dstp[6];
    const int* srcp[6];
    int ablockBase[7];   // prefix over ceil(E/ACHUNK)
    int binBase[7];      // prefix over nBins
    int E[6];
    int offsBase[6];
    int csrBase[6];
    int nDst[6];
    int shift[6];
};

// bin-level histogram (LDS per block, one global atomic per (block,bin))
__global__ __launch_bounds__(256)
void bincount_k(BuildArgs a, int* __restrict__ binCnt) {
    __shared__ int hist[128];
    int blk = blockIdx.x, r = 0;
    #pragma unroll
    for (int k = 1; k <= 5; ++k) if (blk >= a.ablockBase[k]) r = k;
    const int i0 = (blk - a.ablockBase[r]) * ACHUNK;
    const int E = a.E[r], sh = a.shift[r];
    const int tid = threadIdx.x;
    if (tid < 128) hist[tid] = 0;
    __syncthreads();
    #pragma unroll
    for (int k = 0; k < 8; ++k) {
        int i = i0 + k * 256 + tid;
        if (i < E) atomicAdd(&hist[a.dstp[r][i] >> sh], 1);
    }
    __syncthreads();
    if (tid < 128 && hist[tid] > 0)
        atomicAdd(&binCnt[a.binBase[r] + tid], hist[tid]);
}

// single-block scan over all bins (csrBase folds in since bins are in
// relation order and sum(binCnt over r) == E[r])
__global__ void binscan_k(const int* __restrict__ binCnt, int* __restrict__ binOffs,
                          int* __restrict__ binCur, int totBins) {
    __shared__ int buf[1024];
    int tid = threadIdx.x;
    int v = (tid < totBins) ? binCnt[tid] : 0;
    buf[tid] = v;
    __syncthreads();
    #pragma unroll
    for (int off = 1; off < 1024; off <<= 1) {
        int t = (tid >= off) ? buf[tid - off] : 0;
        __syncthreads();
        buf[tid] += t;
        __syncthreads();
    }
    if (tid < totBins) {
        int excl = buf[tid] - v;
        binOffs[tid] = excl;
        binCur[tid]  = excl;
        if (tid == totBins - 1) binOffs[totBins] = buf[tid];
    }
}

// phase A: scatter (src,dst) pairs into bin-ordered staging
__global__ __launch_bounds__(256)
void binscat_k(BuildArgs a, int* __restrict__ binCur, int2* __restrict__ staging) {
    __shared__ int hist[128], hbase[128], hcur[128];
    int blk = blockIdx.x, r = 0;
    #pragma unroll
    for (int k = 1; k <= 5; ++k) if (blk >= a.ablockBase[k]) r = k;
    const int i0 = (blk - a.ablockBase[r]) * ACHUNK;
    const int E = a.E[r], sh = a.shift[r];
    const int tid = threadIdx.x;
    if (tid < 128) { hist[tid] = 0; hcur[tid] = 0; }
    __syncthreads();
    int d[8], s[8], bn[8];
    bool ok[8];
    #pragma unroll
    for (int k = 0; k < 8; ++k) {
        int i = i0 + k * 256 + tid;
        ok[k] = (i < E);
        if (ok[k]) {
            d[k] = a.dstp[r][i];
            s[k] = a.srcp[r][i];
            bn[k] = d[k] >> sh;
            atomicAdd(&hist[bn[k]], 1);
        }
    }
    __syncthreads();
    if (tid < 128 && hist[tid] > 0)
        hbase[tid] = atomicAdd(&binCur[a.binBase[r] + tid], hist[tid]);
    __syncthreads();
    #pragma unroll
    for (int k = 0; k < 8; ++k) {
        if (ok[k]) {
            int lr = atomicAdd(&hcur[bn[k]], 1);
            staging[hbase[bn[k]] + lr] = make_int2(s[k], d[k]);
        }
    }
}

// phase B: one block per bin. Count own nodes from staging (LDS), scan (LDS),
// write offs segment coalesced, place edges into contiguous csr region.
__global__ __launch_bounds__(256)
void binplace2_k(BuildArgs a, const int* __restrict__ binOffs,
                 const int2* __restrict__ staging,
                 int* __restrict__ offsAll, int* __restrict__ csr) {
    __shared__ int cnt[512];
    __shared__ int sbuf[512];
    int g = blockIdx.x, r = 0;
    #pragma unroll
    for (int k = 1; k <= 5; ++k) if (g >= a.binBase[k]) r = k;
    const int b = g - a.binBase[r];
    const int sh = a.shift[r];
    const int dlo = b << sh;
    const int dhi = min(dlo + (1 << sh), a.nDst[r]);
    const int nd = dhi - dlo;
    const int tid = threadIdx.x;
    const int i0 = tid, i1 = tid + 256;
    cnt[i0] = 0; cnt[i1] = 0;
    __syncthreads();
    const int eBase = binOffs[g];
    const int eEnd  = binOffs[g + 1];
    for (int i = eBase + tid; i < eEnd; i += 256)
        atomicAdd(&cnt[staging[i].y - dlo], 1);
    __syncthreads();
    sbuf[i0] = cnt[i0]; sbuf[i1] = cnt[i1];
    __syncthreads();
    #pragma unroll
    for (int off = 1; off < 512; off <<= 1) {
        int t0 = (i0 >= off) ? sbuf[i0 - off] : 0;
        int t1 = (i1 >= off) ? sbuf[i1 - off] : 0;
        __syncthreads();
        sbuf[i0] += t0; sbuf[i1] += t1;
        __syncthreads();
    }
    const int eRel = eBase - a.csrBase[r];   // relation-local edge base
    int e0 = sbuf[i0] - cnt[i0];             // exclusive
    int e1 = sbuf[i1] - cnt[i1];
    if (i0 < nd) { offsAll[a.offsBase[r] + dlo + i0] = eRel + e0; cnt[i0] = eBase + e0; }
    if (i1 < nd) { offsAll[a.offsBase[r] + dlo + i1] = eRel + e1; cnt[i1] = eBase + e1; }
    if (tid == 0 && dhi == a.nDst[r])
        offsAll[a.offsBase[r] + a.nDst[r]] = eRel + (eEnd - eBase);
    __syncthreads();
    for (int i = eBase + tid; i < eEnd; i += 256) {
        int2 p = staging[i];
        int pos = atomicAdd(&cnt[p.y - dlo], 1);
        csr[pos] = p.x;                      // pos is already global (csrBase folded)
    }
}

// ---------------------------------------------- weight prep: bf16 + transpose
__global__ void prep_w_k(const float* __restrict__ Wl, const float* __restrict__ Wr,
                         const float* __restrict__ b,
                         ushort* __restrict__ WlT, ushort* __restrict__ WsumT,
                         float* __restrict__ bsum) {
    const int rA[3] = {3, 0, 1}, rB[3] = {5, 4, 2};
    int blk = blockIdx.x, tid = threadIdx.x;
    int nr = tid >> 1;
    int k0 = (tid & 1) * 64;
    if (blk < 24) {
        const float* src = Wl + (size_t)blk * 16384;
        ushort* dst = WlT + (size_t)blk * 16384;
        for (int k = k0; k < k0 + 64; ++k)
            dst[nr * 128 + k] = f2bf(src[k * 128 + nr]);
    } else {
        int lt = blk - 24, l = lt / 3, t = lt % 3;
        const float* sA = Wr + (size_t)(l * 6 + rA[t]) * 16384;
        const float* sB = Wr + (size_t)(l * 6 + rB[t]) * 16384;
        ushort* dst = WsumT + (size_t)lt * 16384;
        for (int k = k0; k < k0 + 64; ++k)
            dst[nr * 128 + k] = f2bf(sA[k * 128 + nr] + sB[k * 128 + nr]);
        if (tid < 128)
            bsum[lt * 128 + tid] = b[(l * 6 + rA[t]) * 128 + tid] +
                                   b[(l * 6 + rB[t]) * 128 + tid];
    }
}

// ------------------------------------------------------- x -> bf16 h0
__global__ void cvt_x_k(const float* __restrict__ xc, const float* __restrict__ xm,
                        const float* __restrict__ xd, ushort* __restrict__ h) {
    int i = blockIdx.x * 256 + threadIdx.x;
    const int tot = NTOT * H / 8;
    if (i >= tot) return;
    size_t base = (size_t)i * 8;
    int row = (int)(base >> 7);
    const float* src; size_t local;
    if (row < NC_N) { src = xc; local = base; }
    else if (row < NC_N + NM_N) { src = xm; local = base - (size_t)NC_N * H; }
    else { src = xd; local = base - (size_t)(NC_N + NM_N) * H; }
    float4 v0 = *(const float4*)(src + local);
    float4 v1 = *(const float4*)(src + local + 4);
    uint4 o;
    o.x = (uint)f2bf(v0.x) | ((uint)f2bf(v0.y) << 16);
    o.y = (uint)f2bf(v0.z) | ((uint)f2bf(v0.w) << 16);
    o.z = (uint)f2bf(v1.x) | ((uint)f2bf(v1.y) << 16);
    o.w = (uint)f2bf(v1.z) | ((uint)f2bf(v1.w) << 16);
    *(uint4*)(h + base) = o;
}

// ----------------------------------------------------------- segment mean
// All 6 relations of a layer in one dispatch. Per relation: bf16 rows (256B =
// 32 uint2); lanes 0..31 even edge, 32..63 odd edge; 16 edges in flight.
struct AggArgs {
    const ushort* src[6];   // [2t+j]: j=0 -> relA(t), j=1 -> relB(t)
    const int* offs[6];
    const int* csr[6];
    ushort* out[6];
    int n[3];
    int blockBase[4];
    int halfBlocks[3];
};

__global__ __launch_bounds__(256)
void agg_all_k(AggArgs ga) {
    const int b = blockIdx.x;
    const int t = (b >= ga.blockBase[2]) ? 2 : (b >= ga.blockBase[1]) ? 1 : 0;
    const int local = b - ga.blockBase[t];
    const int isB = (local >= ga.halfBlocks[t]) ? 1 : 0;
    const int ridx = 2 * t + isB;
    const uint2* __restrict__ src = (const uint2*)ga.src[ridx];
    const int* __restrict__ offs  = ga.offs[ridx];
    const int* __restrict__ csr   = ga.csr[ridx];
    uint2* __restrict__ out       = (uint2*)ga.out[ridx];
    const int n = ga.n[t];
    const int w = (local - isB * ga.halfBlocks[t]) * 4 + (int)(threadIdx.x >> 6);
    if (w >= n) return;
    const int lane = threadIdx.x & 63;
    const int half = lane >> 5;
    const int lh   = lane & 31;
    const int s = offs[w], e = offs[w + 1];

    float a0 = 0.f, a1 = 0.f, a2 = 0.f, a3 = 0.f;
    int j = s;
    for (; j + 16 <= e; j += 16) {
        int i0 = csr[j + 0  + half], i1 = csr[j + 2  + half];
        int i2 = csr[j + 4  + half], i3 = csr[j + 6  + half];
        int i4 = csr[j + 8  + half], i5 = csr[j + 10 + half];
        int i6 = csr[j + 12 + half], i7 = csr[j + 14 + half];
        uint2 v0 = src[(size_t)i0 * 32 + lh];
        uint2 v1 = src[(size_t)i1 * 32 + lh];
        uint2 v2 = src[(size_t)i2 * 32 + lh];
        uint2 v3 = src[(size_t)i3 * 32 + lh];
        uint2 v4 = src[(size_t)i4 * 32 + lh];
        uint2 v5 = src[(size_t)i5 * 32 + lh];
        uint2 v6 = src[(size_t)i6 * 32 + lh];
        uint2 v7 = src[(size_t)i7 * 32 + lh];
        a0 += bflo(v0.x) + bflo(v1.x) + bflo(v2.x) + bflo(v3.x)
            + bflo(v4.x) + bflo(v5.x) + bflo(v6.x) + bflo(v7.x);
        a1 += bfhi(v0.x) + bfhi(v1.x) + bfhi(v2.x) + bfhi(v3.x)
            + bfhi(v4.x) + bfhi(v5.x) + bfhi(v6.x) + bfhi(v7.x);
        a2 += bflo(v0.y) + bflo(v1.y) + bflo(v2.y) + bflo(v3.y)
            + bflo(v4.y) + bflo(v5.y) + bflo(v6.y) + bflo(v7.y);
        a3 += bfhi(v0.y) + bfhi(v1.y) + bfhi(v2.y) + bfhi(v3.y)
            + bfhi(v4.y) + bfhi(v5.y) + bfhi(v6.y) + bfhi(v7.y);
    }
    for (; j + 2 <= e; j += 2) {
        int i0 = csr[j + half];
        uint2 v = src[(size_t)i0 * 32 + lh];
        a0 += bflo(v.x); a1 += bfhi(v.x); a2 += bflo(v.y); a3 += bfhi(v.y);
    }
    if (j < e && half == 0) {
        int i0 = csr[j];
        uint2 v = src[(size_t)i0 * 32 + lh];
        a0 += bflo(v.x); a1 += bfhi(v.x); a2 += bflo(v.y); a3 += bfhi(v.y);
    }
    a0 += __shfl_xor(a0, 32);
    a1 += __shfl_xor(a1, 32);
    a2 += __shfl_xor(a2, 32);
    a3 += __shfl_xor(a3, 32);
    if (half == 0) {
        const float inv = 1.0f / fmaxf((float)(e - s), 1.0f);
        uint2 o;
        o.x = (uint)f2bf(a0 * inv) | ((uint)f2bf(a1 * inv) << 16);
        o.y = (uint)f2bf(a2 * inv) | ((uint)f2bf(a3 * inv) << 16);
        out[(size_t)w * 32 + lh] = o;
    }
}

// ------------------------------------------------------------ MFMA GEMM
// All 3 dst types in one dispatch. mode 0: relu -> bf16; mode 1: fused
// L2-normalize -> fp32 (the 16 lr-lanes of an lk-group hold one full row).
struct GemmArgs {
    const ushort* A1[3]; const ushort* W1[3];
    const ushort* A2[3]; const ushort* W2[3];
    const ushort* A3[3]; const ushort* W3[3];
    const float* bias[3];
    void* out[3];
    int n[3];
    int blockBase[4];
    int mode;
};

__global__ __launch_bounds__(256)
void gemm_all_k(GemmArgs ga) {
    __shared__ ushort As[128][40];
    __shared__ ushort Bs[128][40];
    const int b = blockIdx.x;
    const int t = (b >= ga.blockBase[2]) ? 2 : (b >= ga.blockBase[1]) ? 1 : 0;
    const int tid  = threadIdx.x;
    const int wave = tid >> 6, lane = tid & 63;
    const int lr = lane & 15, lk = lane >> 4;
    const int row0 = (b - ga.blockBase[t]) * 128;
    const int n = ga.n[t];

    f32x4 acc[2][8];
    #pragma unroll
    for (int i = 0; i < 2; ++i)
        #pragma unroll
        for (int j = 0; j < 8; ++j) acc[i][j] = (f32x4)0.f;

    const ushort* Ap[3] = {ga.A1[t], ga.A2[t], ga.A3[t]};
    const ushort* Wp[3] = {ga.W1[t], ga.W2[t], ga.W3[t]};

    const int rs = tid >> 2;
    const int kb = (tid & 3) * 8;

    for (int term = 0; term < 3; ++term) {
        const ushort* A = Ap[term];
        const ushort* W = Wp[term];
        #pragma unroll 1
        for (int k0 = 0; k0 < 128; k0 += 32) {
            #pragma unroll
            for (int p = 0; p < 2; ++p) {
                int rr = rs + p * 64;
                int gr = row0 + rr;
                short8 av = (short8)0;
                if (gr < n) av = *(const short8*)(A + (size_t)gr * 128 + k0 + kb);
                *(short8*)&As[rr][kb] = av;
                short8 wv = *(const short8*)(W + (size_t)rr * 128 + k0 + kb);
                *(short8*)&Bs[rr][kb] = wv;
            }
            __syncthreads();
            short8 af0 = *(const short8*)&As[wave * 32 + lr][lk * 8];
            short8 af1 = *(const short8*)&As[wave * 32 + 16 + lr][lk * 8];
            #pragma unroll
            for (int nt = 0; nt < 8; ++nt) {
                short8 bf = *(const short8*)&Bs[nt * 16 + lr][lk * 8];
                acc[0][nt] = __builtin_amdgcn_mfma_f32_16x16x32_bf16(af0, bf, acc[0][nt], 0, 0, 0);
                acc[1][nt] = __builtin_amdgcn_mfma_f32_16x16x32_bf16(af1, bf, acc[1][nt], 0, 0, 0);
            }
            __syncthreads();
        }
    }
    float bv[8];
    #pragma unroll
    for (int nt = 0; nt < 8; ++nt) bv[nt] = ga.bias[t][nt * 16 + lr];

    if (ga.mode == 0) {
        ushort* outp = (ushort*)ga.out[t];
        #pragma unroll
        for (int mt = 0; mt < 2; ++mt) {
            #pragma unroll
            for (int nt = 0; nt < 8; ++nt) {
                int col = nt * 16 + lr;
                #pragma unroll
                for (int r = 0; r < 4; ++r) {
                    int row = row0 + wave * 32 + mt * 16 + lk * 4 + r;
                    if (row < n) {
                        float v = fmaxf(0.5f * (acc[mt][nt][r] + bv[nt]), 0.f);
                        outp[(size_t)row * 128 + col] = f2bf(v);
                    }
                }
            }
        }
    } else {
        float* outp = (float*)ga.out[t];
        #pragma unroll
        for (int mt = 0; mt < 2; ++mt) {
            #pragma unroll
            for (int r = 0; r < 4; ++r) {
                float v[8]; float ss = 0.f;
                #pragma unroll
                for (int nt = 0; nt < 8; ++nt) {
                    v[nt] = 0.5f * (acc[mt][nt][r] + bv[nt]);
                    ss += v[nt] * v[nt];
                }
                ss += __shfl_xor(ss, 1);
                ss += __shfl_xor(ss, 2);
                ss += __shfl_xor(ss, 4);
                ss += __shfl_xor(ss, 8);
                float scale = 1.0f / fmaxf(sqrtf(ss), 1e-12f);
                int row = row0 + wave * 32 + mt * 16 + lk * 4 + r;
                if (row < n) {
                    #pragma unroll
                    for (int nt = 0; nt < 8; ++nt)
                        outp[(size_t)row * 128 + nt * 16 + lr] = v[nt] * scale;
                }
            }
        }
    }
}

// ---------------------------------------------------------------- launch
extern "C" void kernel_launch(void* const* d_in, const int* in_sizes, int n_in,
                              void* d_out, int out_size, void* d_ws, size_t ws_size,
                              hipStream_t stream) {
    const float* x[3] = {(const float*)d_in[0], (const float*)d_in[1], (const float*)d_in[2]};
    const int* srcp[6] = {(const int*)d_in[3], (const int*)d_in[5], (const int*)d_in[7],
                          (const int*)d_in[9], (const int*)d_in[11], (const int*)d_in[13]};
    const int* dstp[6] = {(const int*)d_in[4], (const int*)d_in[6], (const int*)d_in[8],
                          (const int*)d_in[10], (const int*)d_in[12], (const int*)d_in[14]};
    const float* Wl = (const float*)d_in[15];
    const float* Wr = (const float*)d_in[16];
    const float* b  = (const float*)d_in[17];
    float* outp = (float*)d_out;

    const int nNode[3]   = {NC_N, NM_N, ND_N};
    const int E[6]       = {800000, 400000, 800000, 800000, 400000, 800000};
    const int nDst[6]    = {NM_N, ND_N, ND_N, NC_N, NM_N, NC_N};
    const int shiftR[6]  = {8, 7, 7, 9, 8, 9};   // bins of 128-512 dst nodes
    const int srcType[6] = {0, 1, 0, 1, 2, 2};
    const int relA[3] = {3, 0, 1}, relB[3] = {5, 4, 2};

    // ---- workspace carve-up (256B aligned), ~110 MB
    char* p = (char*)d_ws;
    auto alloc = [&](size_t bytes) -> char* {
        char* r = p; p += (bytes + 255) & ~(size_t)255; return r;
    };
    ushort* hA    = (ushort*)alloc((size_t)NTOT * H * 2);
    ushort* hB    = (ushort*)alloc((size_t)NTOT * H * 2);
    ushort* aggA[3], * aggB[3];
    for (int t = 0; t < 3; ++t) {
        aggA[t] = (ushort*)alloc((size_t)nNode[t] * H * 2);
        aggB[t] = (ushort*)alloc((size_t)nNode[t] * H * 2);
    }
    ushort* WlT   = (ushort*)alloc((size_t)24 * H * H * 2);
    ushort* WsumT = (ushort*)alloc((size_t)12 * H * H * 2);
    float*  bsum  = (float*)alloc((size_t)12 * H * 4);
    int*    offs  = (int*)alloc((size_t)180006 * 4);
    int*    csr   = (int*)alloc((size_t)4000000 * 4);
    int*    binCnt  = (int*)alloc((size_t)1024 * 4);
    int*    binOffs = (int*)alloc((size_t)1025 * 4);
    int*    binCur  = (int*)alloc((size_t)1024 * 4);
    // staging (32MB) aliases hA+hB (46MB) — consumed before cvt_x / layer-0 gemm
    int2*   staging = (int2*)hA;

    BuildArgs ba;
    int totBins = 0;
    { int ob = 0, cb = 0, ab = 0, gb = 0;
      for (int r = 0; r < 6; ++r) {
          ba.dstp[r] = dstp[r]; ba.srcp[r] = srcp[r];
          ba.E[r] = E[r]; ba.nDst[r] = nDst[r]; ba.shift[r] = shiftR[r];
          ba.ablockBase[r] = ab; ab += (E[r] + ACHUNK - 1) / ACHUNK;
          ba.binBase[r]    = gb; gb += (nDst[r] + (1 << shiftR[r]) - 1) >> shiftR[r];
          ba.offsBase[r] = ob; ob += nDst[r] + 1;
          ba.csrBase[r]  = cb; cb += E[r];
      }
      ba.ablockBase[6] = ab; ba.binBase[6] = gb;
      totBins = gb; }

    // ---- CSR build (once, reused by all layers)
    hipMemsetAsync(binCnt, 0, totBins * 4, stream);
    bincount_k<<<ba.ablockBase[6], 256, 0, stream>>>(ba, binCnt);
    binscan_k<<<1, 1024, 0, stream>>>(binCnt, binOffs, binCur, totBins);
    binscat_k<<<ba.ablockBase[6], 256, 0, stream>>>(ba, binCur, staging);
    binplace2_k<<<totBins, 256, 0, stream>>>(ba, binOffs, staging, offs, csr);

    prep_w_k<<<36, 256, 0, stream>>>(Wl, Wr, b, WlT, WsumT, bsum);
    cvt_x_k<<<(NTOT * H / 8 + 255) / 256, 256, 0, stream>>>(x[0], x[1], x[2], hA);

    const size_t tOff[3] = {0, (size_t)NC_N * H, (size_t)(NC_N + NM_N) * H};
    ushort* hb[2] = {hA, hB};

    int cur = 0;
    for (int l = 0; l < 4; ++l) {
        ushort* hsrc = hb[cur];
        ushort* hdst = hb[cur ^ 1];

        AggArgs aa;
        int aggBlocks = 0;
        for (int t = 0; t < 3; ++t) {
            int rA = relA[t], rB = relB[t];
            aa.src[2 * t]     = hsrc + tOff[srcType[rA]];
            aa.offs[2 * t]    = offs + ba.offsBase[rA];
            aa.csr[2 * t]     = csr + ba.csrBase[rA];
            aa.out[2 * t]     = aggA[t];
            aa.src[2 * t + 1] = hsrc + tOff[srcType[rB]];
            aa.offs[2 * t + 1]= offs + ba.offsBase[rB];
            aa.csr[2 * t + 1] = csr + ba.csrBase[rB];
            aa.out[2 * t + 1] = aggB[t];
            aa.n[t] = nNode[t];
            aa.halfBlocks[t] = (nNode[t] + 3) / 4;
            aa.blockBase[t] = aggBlocks;
            aggBlocks += 2 * aa.halfBlocks[t];
        }
        aa.blockBase[3] = aggBlocks;
        agg_all_k<<<aggBlocks, 256, 0, stream>>>(aa);

        GemmArgs ga;
        int gemmBlocks = 0;
        for (int t = 0; t < 3; ++t) {
            int rA = relA[t], rB = relB[t];
            ga.A1[t] = aggA[t]; ga.W1[t] = WlT + (size_t)(l * 6 + rA) * H * H;
            ga.A2[t] = aggB[t]; ga.W2[t] = WlT + (size_t)(l * 6 + rB) * H * H;
            ga.A3[t] = hsrc + tOff[t];
            ga.W3[t] = WsumT + (size_t)(l * 3 + t) * H * H;
            ga.bias[t] = bsum + (size_t)(l * 3 + t) * H;
            ga.out[t] = (l < 3) ? (void*)(hdst + tOff[t]) : (void*)(outp + tOff[t]);
            ga.n[t] = nNode[t];
            ga.blockBase[t] = gemmBlocks;
            gemmBlocks += (nNode[t] + 127) / 128;
        }
        ga.blockBase[3] = gemmBlocks;
        ga.mode = (l < 3) ? 0 : 1;
        gemm_all_k<<<gemmBlocks, 256, 0, stream>>>(ga);

        cur ^= 1;
    }
}

// Round 8
// 835.121 us; speedup vs baseline: 4.0438x; 1.0501x over previous
//
#include <hip/hip_runtime.h>
#include <hip/hip_bf16.h>

// HeteroGraphSAGE on MI355X — round 7.
// Round-6 profile: agg_all_k 4x138us = 63% (VALUBusy 51%, tail-loop latency
// chains on avg-degree-16..27 nodes). Change: CSR segments padded to 16-edge
// multiples with zero-row indices -> agg loop is branch-free, always MLP-8.
// binplace2 computes raw+padded offsets (two LDS scans), fills pad slots with
// per-relation zero index. Zero row = row 90000 of hA/hB (memset per call).

#define NC_N 50000
#define NM_N 30000
#define ND_N 10000
#define NTOT 90000
#define H    128
#define PADG 16   // csr segment padding granularity

typedef __attribute__((ext_vector_type(8))) short short8;
typedef __attribute__((ext_vector_type(4))) float f32x4;

__device__ __forceinline__ ushort f2bf(float f) {
    uint u = __float_as_uint(f);
    return (ushort)((u + 0x7fffu + ((u >> 16) & 1u)) >> 16);   // RNE
}
__device__ __forceinline__ float bflo(uint v) { return __uint_as_float(v << 16); }
__device__ __forceinline__ float bfhi(uint v) { return __uint_as_float(v & 0xffff0000u); }

// ---------------------------------------------------------------- CSR build
#define ACHUNK 2048   // edges per phase-A block

struct BuildArgs {
    const int* dstp[6];
    const int* srcp[6];
    int ablockBase[7];   // prefix over ceil(E/ACHUNK)
    int binBase[7];      // prefix over nBins
    int E[6];
    int offsBase[6];
    int csrBase[6];
    int nDst[6];
    int shift[6];
    int padBase[6];      // cumulative pad allowance before relation r
    int zIdx[6];         // per-relation zero-row index (rel-local)
};

// bin-level histogram (LDS per block, one global atomic per (block,bin))
__global__ __launch_bounds__(256)
void bincount_k(BuildArgs a, int* __restrict__ binCnt) {
    __shared__ int hist[128];
    int blk = blockIdx.x, r = 0;
    #pragma unroll
    for (int k = 1; k <= 5; ++k) if (blk >= a.ablockBase[k]) r = k;
    const int i0 = (blk - a.ablockBase[r]) * ACHUNK;
    const int E = a.E[r], sh = a.shift[r];
    const int tid = threadIdx.x;
    if (tid < 128) hist[tid] = 0;
    __syncthreads();
    #pragma unroll
    for (int k = 0; k < 8; ++k) {
        int i = i0 + k * 256 + tid;
        if (i < E) atomicAdd(&hist[a.dstp[r][i] >> sh], 1);
    }
    __syncthreads();
    if (tid < 128 && hist[tid] > 0)
        atomicAdd(&binCnt[a.binBase[r] + tid], hist[tid]);
}

// single-block scan over all bins (raw edge counts; csrBase folds in)
__global__ void binscan_k(const int* __restrict__ binCnt, int* __restrict__ binOffs,
                          int* __restrict__ binCur, int totBins) {
    __shared__ int buf[1024];
    int tid = threadIdx.x;
    int v = (tid < totBins) ? binCnt[tid] : 0;
    buf[tid] = v;
    __syncthreads();
    #pragma unroll
    for (int off = 1; off < 1024; off <<= 1) {
        int t = (tid >= off) ? buf[tid - off] : 0;
        __syncthreads();
        buf[tid] += t;
        __syncthreads();
    }
    if (tid < totBins) {
        int excl = buf[tid] - v;
        binOffs[tid] = excl;
        binCur[tid]  = excl;
        if (tid == totBins - 1) binOffs[totBins] = buf[tid];
    }
}

// phase A: scatter (src,dst) pairs into bin-ordered staging
__global__ __launch_bounds__(256)
void binscat_k(BuildArgs a, int* __restrict__ binCur, int2* __restrict__ staging) {
    __shared__ int hist[128], hbase[128], hcur[128];
    int blk = blockIdx.x, r = 0;
    #pragma unroll
    for (int k = 1; k <= 5; ++k) if (blk >= a.ablockBase[k]) r = k;
    const int i0 = (blk - a.ablockBase[r]) * ACHUNK;
    const int E = a.E[r], sh = a.shift[r];
    const int tid = threadIdx.x;
    if (tid < 128) { hist[tid] = 0; hcur[tid] = 0; }
    __syncthreads();
    int d[8], s[8], bn[8];
    bool ok[8];
    #pragma unroll
    for (int k = 0; k < 8; ++k) {
        int i = i0 + k * 256 + tid;
        ok[k] = (i < E);
        if (ok[k]) {
            d[k] = a.dstp[r][i];
            s[k] = a.srcp[r][i];
            bn[k] = d[k] >> sh;
            atomicAdd(&hist[bn[k]], 1);
        }
    }
    __syncthreads();
    if (tid < 128 && hist[tid] > 0)
        hbase[tid] = atomicAdd(&binCur[a.binBase[r] + tid], hist[tid]);
    __syncthreads();
    #pragma unroll
    for (int k = 0; k < 8; ++k) {
        if (ok[k]) {
            int lr = atomicAdd(&hcur[bn[k]], 1);
            staging[hbase[bn[k]] + lr] = make_int2(s[k], d[k]);
        }
    }
}

// phase B: one block per bin. LDS node-count; raw scan (-> offs for degree);
// padded scan (-> poffs, global padded csr positions); pad-fill zero indices;
// place real edges via LDS cursors.
__global__ __launch_bounds__(256)
void binplace2_k(BuildArgs a, const int* __restrict__ binOffs,
                 const int2* __restrict__ staging,
                 int* __restrict__ offsAll, int* __restrict__ poffsAll,
                 int* __restrict__ csr) {
    __shared__ int cnt[512];
    __shared__ int sbuf[512];
    int g = blockIdx.x, r = 0;
    #pragma unroll
    for (int k = 1; k <= 5; ++k) if (g >= a.binBase[k]) r = k;
    const int b = g - a.binBase[r];
    const int sh = a.shift[r];
    const int dlo = b << sh;
    const int dhi = min(dlo + (1 << sh), a.nDst[r]);
    const int nd = dhi - dlo;
    const int tid = threadIdx.x;
    const int i0 = tid, i1 = tid + 256;
    cnt[i0] = 0; cnt[i1] = 0;
    __syncthreads();
    const int eBase = binOffs[g];
    const int eEnd  = binOffs[g + 1];
    for (int i = eBase + tid; i < eEnd; i += 256)
        atomicAdd(&cnt[staging[i].y - dlo], 1);
    __syncthreads();
    const int c0 = cnt[i0], c1 = cnt[i1];
    // raw exclusive scan
    sbuf[i0] = c0; sbuf[i1] = c1;
    __syncthreads();
    #pragma unroll
    for (int off = 1; off < 512; off <<= 1) {
        int t0 = (i0 >= off) ? sbuf[i0 - off] : 0;
        int t1 = (i1 >= off) ? sbuf[i1 - off] : 0;
        __syncthreads();
        sbuf[i0] += t0; sbuf[i1] += t1;
        __syncthreads();
    }
    const int rawe0 = sbuf[i0] - c0, rawe1 = sbuf[i1] - c1;
    // padded exclusive scan
    const int p0c = (c0 + PADG - 1) & ~(PADG - 1);
    const int p1c = (c1 + PADG - 1) & ~(PADG - 1);
    sbuf[i0] = p0c; sbuf[i1] = p1c;
    __syncthreads();
    #pragma unroll
    for (int off = 1; off < 512; off <<= 1) {
        int t0 = (i0 >= off) ? sbuf[i0 - off] : 0;
        int t1 = (i1 >= off) ? sbuf[i1 - off] : 0;
        __syncthreads();
        sbuf[i0] += t0; sbuf[i1] += t1;
        __syncthreads();
    }
    const int pe0 = sbuf[i0] - p0c, pe1 = sbuf[i1] - p1c;
    const int eRel = eBase - a.csrBase[r];
    const int pBin = eBase + a.padBase[r] + b * ((1 << sh) * (PADG - 1));
    const int zI = a.zIdx[r];
    if (i0 < nd) {
        offsAll[a.offsBase[r] + dlo + i0]  = eRel + rawe0;
        poffsAll[a.offsBase[r] + dlo + i0] = pBin + pe0;
        for (int k = c0; k < p0c; ++k) csr[pBin + pe0 + k] = zI;
    }
    if (i1 < nd) {
        offsAll[a.offsBase[r] + dlo + i1]  = eRel + rawe1;
        poffsAll[a.offsBase[r] + dlo + i1] = pBin + pe1;
        for (int k = c1; k < p1c; ++k) csr[pBin + pe1 + k] = zI;
    }
    if (tid == 0 && dhi == a.nDst[r])
        offsAll[a.offsBase[r] + a.nDst[r]] = eRel + (eEnd - eBase);
    __syncthreads();
    if (i0 < nd) cnt[i0] = pBin + pe0;
    if (i1 < nd) cnt[i1] = pBin + pe1;
    __syncthreads();
    for (int i = eBase + tid; i < eEnd; i += 256) {
        int2 pv = staging[i];
        int pos = atomicAdd(&cnt[pv.y - dlo], 1);
        csr[pos] = pv.x;
    }
}

// ---------------------------------------------- weight prep: bf16 + transpose
__global__ void prep_w_k(const float* __restrict__ Wl, const float* __restrict__ Wr,
                         const float* __restrict__ b,
                         ushort* __restrict__ WlT, ushort* __restrict__ WsumT,
                         float* __restrict__ bsum) {
    const int rA[3] = {3, 0, 1}, rB[3] = {5, 4, 2};
    int blk = blockIdx.x, tid = threadIdx.x;
    int nr = tid >> 1;
    int k0 = (tid & 1) * 64;
    if (blk < 24) {
        const float* src = Wl + (size_t)blk * 16384;
        ushort* dst = WlT + (size_t)blk * 16384;
        for (int k = k0; k < k0 + 64; ++k)
            dst[nr * 128 + k] = f2bf(src[k * 128 + nr]);
    } else {
        int lt = blk - 24, l = lt / 3, t = lt % 3;
        const float* sA = Wr + (size_t)(l * 6 + rA[t]) * 16384;
        const float* sB = Wr + (size_t)(l * 6 + rB[t]) * 16384;
        ushort* dst = WsumT + (size_t)lt * 16384;
        for (int k = k0; k < k0 + 64; ++k)
            dst[nr * 128 + k] = f2bf(sA[k * 128 + nr] + sB[k * 128 + nr]);
        if (tid < 128)
            bsum[lt * 128 + tid] = b[(l * 6 + rA[t]) * 128 + tid] +
                                   b[(l * 6 + rB[t]) * 128 + tid];
    }
}

// ------------------------------------------------------- x -> bf16 h0
__global__ void cvt_x_k(const float* __restrict__ xc, const float* __restrict__ xm,
                        const float* __restrict__ xd, ushort* __restrict__ h) {
    int i = blockIdx.x * 256 + threadIdx.x;
    const int tot = NTOT * H / 8;
    if (i >= tot) return;
    size_t base = (size_t)i * 8;
    int row = (int)(base >> 7);
    const float* src; size_t local;
    if (row < NC_N) { src = xc; local = base; }
    else if (row < NC_N + NM_N) { src = xm; local = base - (size_t)NC_N * H; }
    else { src = xd; local = base - (size_t)(NC_N + NM_N) * H; }
    float4 v0 = *(const float4*)(src + local);
    float4 v1 = *(const float4*)(src + local + 4);
    uint4 o;
    o.x = (uint)f2bf(v0.x) | ((uint)f2bf(v0.y) << 16);
    o.y = (uint)f2bf(v0.z) | ((uint)f2bf(v0.w) << 16);
    o.z = (uint)f2bf(v1.x) | ((uint)f2bf(v1.y) << 16);
    o.w = (uint)f2bf(v1.z) | ((uint)f2bf(v1.w) << 16);
    *(uint4*)(h + base) = o;
}

// ----------------------------------------------------------- segment mean
// All 6 relations in one dispatch. Padded csr -> single branch-free MLP-8
// loop (16 edges/iter). poffs = global padded start; offs gives true degree.
struct AggArgs {
    const ushort* src[6];
    const int* offs[6];    // raw offsets (degree)
    const int* poffs[6];   // padded global start positions
    ushort* out[6];
    int n[3];
    int blockBase[4];
    int halfBlocks[3];
};

__global__ __launch_bounds__(256)
void agg_all_k(AggArgs ga, const int* __restrict__ csr) {
    const int b = blockIdx.x;
    const int t = (b >= ga.blockBase[2]) ? 2 : (b >= ga.blockBase[1]) ? 1 : 0;
    const int local = b - ga.blockBase[t];
    const int isB = (local >= ga.halfBlocks[t]) ? 1 : 0;
    const int ridx = 2 * t + isB;
    const uint2* __restrict__ src = (const uint2*)ga.src[ridx];
    const int* __restrict__ offs  = ga.offs[ridx];
    const int* __restrict__ poffs = ga.poffs[ridx];
    uint2* __restrict__ out       = (uint2*)ga.out[ridx];
    const int n = ga.n[t];
    const int w = (local - isB * ga.halfBlocks[t]) * 4 + (int)(threadIdx.x >> 6);
    if (w >= n) return;
    const int lane = threadIdx.x & 63;
    const int half = lane >> 5;
    const int lh   = lane & 31;
    const int deg  = offs[w + 1] - offs[w];
    const int ps   = poffs[w];
    const int pe   = ps + ((deg + PADG - 1) & ~(PADG - 1));

    float a0 = 0.f, a1 = 0.f, a2 = 0.f, a3 = 0.f;
    for (int j = ps; j < pe; j += 16) {
        int i0 = csr[j + 0  + half], i1 = csr[j + 2  + half];
        int i2 = csr[j + 4  + half], i3 = csr[j + 6  + half];
        int i4 = csr[j + 8  + half], i5 = csr[j + 10 + half];
        int i6 = csr[j + 12 + half], i7 = csr[j + 14 + half];
        uint2 v0 = src[(size_t)i0 * 32 + lh];
        uint2 v1 = src[(size_t)i1 * 32 + lh];
        uint2 v2 = src[(size_t)i2 * 32 + lh];
        uint2 v3 = src[(size_t)i3 * 32 + lh];
        uint2 v4 = src[(size_t)i4 * 32 + lh];
        uint2 v5 = src[(size_t)i5 * 32 + lh];
        uint2 v6 = src[(size_t)i6 * 32 + lh];
        uint2 v7 = src[(size_t)i7 * 32 + lh];
        a0 += bflo(v0.x) + bflo(v1.x) + bflo(v2.x) + bflo(v3.x)
            + bflo(v4.x) + bflo(v5.x) + bflo(v6.x) + bflo(v7.x);
        a1 += bfhi(v0.x) + bfhi(v1.x) + bfhi(v2.x) + bfhi(v3.x)
            + bfhi(v4.x) + bfhi(v5.x) + bfhi(v6.x) + bfhi(v7.x);
        a2 += bflo(v0.y) + bflo(v1.y) + bflo(v2.y) + bflo(v3.y)
            + bflo(v4.y) + bflo(v5.y) + bflo(v6.y) + bflo(v7.y);
        a3 += bfhi(v0.y) + bfhi(v1.y) + bfhi(v2.y) + bfhi(v3.y)
            + bfhi(v4.y) + bfhi(v5.y) + bfhi(v6.y) + bfhi(v7.y);
    }
    a0 += __shfl_xor(a0, 32);
    a1 += __shfl_xor(a1, 32);
    a2 += __shfl_xor(a2, 32);
    a3 += __shfl_xor(a3, 32);
    if (half == 0) {
        const float inv = 1.0f / fmaxf((float)deg, 1.0f);
        uint2 o;
        o.x = (uint)f2bf(a0 * inv) | ((uint)f2bf(a1 * inv) << 16);
        o.y = (uint)f2bf(a2 * inv) | ((uint)f2bf(a3 * inv) << 16);
        out[(size_t)w * 32 + lh] = o;
    }
}

// ------------------------------------------------------------ MFMA GEMM
struct GemmArgs {
    const ushort* A1[3]; const ushort* W1[3];
    const ushort* A2[3]; const ushort* W2[3];
    const ushort* A3[3]; const ushort* W3[3];
    const float* bias[3];
    void* out[3];
    int n[3];
    int blockBase[4];
    int mode;
};

__global__ __launch_bounds__(256)
void gemm_all_k(GemmArgs ga) {
    __shared__ ushort As[128][40];
    __shared__ ushort Bs[128][40];
    const int b = blockIdx.x;
    const int t = (b >= ga.blockBase[2]) ? 2 : (b >= ga.blockBase[1]) ? 1 : 0;
    const int tid  = threadIdx.x;
    const int wave = tid >> 6, lane = tid & 63;
    const int lr = lane & 15, lk = lane >> 4;
    const int row0 = (b - ga.blockBase[t]) * 128;
    const int n = ga.n[t];

    f32x4 acc[2][8];
    #pragma unroll
    for (int i = 0; i < 2; ++i)
        #pragma unroll
        for (int j = 0; j < 8; ++j) acc[i][j] = (f32x4)0.f;

    const ushort* Ap[3] = {ga.A1[t], ga.A2[t], ga.A3[t]};
    const ushort* Wp[3] = {ga.W1[t], ga.W2[t], ga.W3[t]};

    const int rs = tid >> 2;
    const int kb = (tid & 3) * 8;

    for (int term = 0; term < 3; ++term) {
        const ushort* A = Ap[term];
        const ushort* W = Wp[term];
        #pragma unroll 1
        for (int k0 = 0; k0 < 128; k0 += 32) {
            #pragma unroll
            for (int p = 0; p < 2; ++p) {
                int rr = rs + p * 64;
                int gr = row0 + rr;
                short8 av = (short8)0;
                if (gr < n) av = *(const short8*)(A + (size_t)gr * 128 + k0 + kb);
                *(short8*)&As[rr][kb] = av;
                short8 wv = *(const short8*)(W + (size_t)rr * 128 + k0 + kb);
                *(short8*)&Bs[rr][kb] = wv;
            }
            __syncthreads();
            short8 af0 = *(const short8*)&As[wave * 32 + lr][lk * 8];
            short8 af1 = *(const short8*)&As[wave * 32 + 16 + lr][lk * 8];
            #pragma unroll
            for (int nt = 0; nt < 8; ++nt) {
                short8 bf = *(const short8*)&Bs[nt * 16 + lr][lk * 8];
                acc[0][nt] = __builtin_amdgcn_mfma_f32_16x16x32_bf16(af0, bf, acc[0][nt], 0, 0, 0);
                acc[1][nt] = __builtin_amdgcn_mfma_f32_16x16x32_bf16(af1, bf, acc[1][nt], 0, 0, 0);
            }
            __syncthreads();
        }
    }
    float bv[8];
    #pragma unroll
    for (int nt = 0; nt < 8; ++nt) bv[nt] = ga.bias[t][nt * 16 + lr];

    if (ga.mode == 0) {
        ushort* outp = (ushort*)ga.out[t];
        #pragma unroll
        for (int mt = 0; mt < 2; ++mt) {
            #pragma unroll
            for (int nt = 0; nt < 8; ++nt) {
                int col = nt * 16 + lr;
                #pragma unroll
                for (int r = 0; r < 4; ++r) {
                    int row = row0 + wave * 32 + mt * 16 + lk * 4 + r;
                    if (row < n) {
                        float v = fmaxf(0.5f * (acc[mt][nt][r] + bv[nt]), 0.f);
                        outp[(size_t)row * 128 + col] = f2bf(v);
                    }
                }
            }
        }
    } else {
        float* outp = (float*)ga.out[t];
        #pragma unroll
        for (int mt = 0; mt < 2; ++mt) {
            #pragma unroll
            for (int r = 0; r < 4; ++r) {
                float v[8]; float ss = 0.f;
                #pragma unroll
                for (int nt = 0; nt < 8; ++nt) {
                    v[nt] = 0.5f * (acc[mt][nt][r] + bv[nt]);
                    ss += v[nt] * v[nt];
                }
                ss += __shfl_xor(ss, 1);
                ss += __shfl_xor(ss, 2);
                ss += __shfl_xor(ss, 4);
                ss += __shfl_xor(ss, 8);
                float scale = 1.0f / fmaxf(sqrtf(ss), 1e-12f);
                int row = row0 + wave * 32 + mt * 16 + lk * 4 + r;
                if (row < n) {
                    #pragma unroll
                    for (int nt = 0; nt < 8; ++nt)
                        outp[(size_t)row * 128 + nt * 16 + lr] = v[nt] * scale;
                }
            }
        }
    }
}

// ---------------------------------------------------------------- launch
extern "C" void kernel_launch(void* const* d_in, const int* in_sizes, int n_in,
                              void* d_out, int out_size, void* d_ws, size_t ws_size,
                              hipStream_t stream) {
    const float* x[3] = {(const float*)d_in[0], (const float*)d_in[1], (const float*)d_in[2]};
    const int* srcp[6] = {(const int*)d_in[3], (const int*)d_in[5], (const int*)d_in[7],
                          (const int*)d_in[9], (const int*)d_in[11], (const int*)d_in[13]};
    const int* dstp[6] = {(const int*)d_in[4], (const int*)d_in[6], (const int*)d_in[8],
                          (const int*)d_in[10], (const int*)d_in[12], (const int*)d_in[14]};
    const float* Wl = (const float*)d_in[15];
    const float* Wr = (const float*)d_in[16];
    const float* b  = (const float*)d_in[17];
    float* outp = (float*)d_out;

    const int nNode[3]   = {NC_N, NM_N, ND_N};
    const int E[6]       = {800000, 400000, 800000, 800000, 400000, 800000};
    const int nDst[6]    = {NM_N, ND_N, ND_N, NC_N, NM_N, NC_N};
    const int shiftR[6]  = {8, 7, 7, 9, 8, 9};
    const int srcType[6] = {0, 1, 0, 1, 2, 2};
    const int relA[3] = {3, 0, 1}, relB[3] = {5, 4, 2};
    const int srcRowOff[3] = {0, NC_N, NC_N + NM_N};

    // ---- workspace carve-up (256B aligned)
    char* p = (char*)d_ws;
    auto alloc = [&](size_t bytes) -> char* {
        char* r = p; p += (bytes + 255) & ~(size_t)255; return r;
    };
    ushort* hA    = (ushort*)alloc((size_t)(NTOT + 1) * H * 2);  // +1 zero row
    ushort* hB    = (ushort*)alloc((size_t)(NTOT + 1) * H * 2);
    ushort* aggA[3], * aggB[3];
    for (int t = 0; t < 3; ++t) {
        aggA[t] = (ushort*)alloc((size_t)nNode[t] * H * 2);
        aggB[t] = (ushort*)alloc((size_t)nNode[t] * H * 2);
    }
    ushort* WlT   = (ushort*)alloc((size_t)24 * H * H * 2);
    ushort* WsumT = (ushort*)alloc((size_t)12 * H * H * 2);
    float*  bsum  = (float*)alloc((size_t)12 * H * 4);
    int*    offs  = (int*)alloc((size_t)180006 * 4);
    int*    poffs = (int*)alloc((size_t)180006 * 4);
    int*    binCnt  = (int*)alloc((size_t)1024 * 4);
    int*    binOffs = (int*)alloc((size_t)1025 * 4);
    int*    binCur  = (int*)alloc((size_t)1024 * 4);
    // staging (32MB) aliases hA+hB (46MB) — consumed before cvt_x/zero-row
    int2*   staging = (int2*)hA;

    BuildArgs ba;
    int totBins = 0, padTot = 0;
    { int ob = 0, cb = 0, ab = 0, gb = 0, pb = 0;
      for (int r = 0; r < 6; ++r) {
          ba.dstp[r] = dstp[r]; ba.srcp[r] = srcp[r];
          ba.E[r] = E[r]; ba.nDst[r] = nDst[r]; ba.shift[r] = shiftR[r];
          ba.zIdx[r] = NTOT - srcRowOff[srcType[r]];
          ba.ablockBase[r] = ab; ab += (E[r] + ACHUNK - 1) / ACHUNK;
          int nb = (nDst[r] + (1 << shiftR[r]) - 1) >> shiftR[r];
          ba.binBase[r] = gb; gb += nb;
          ba.offsBase[r] = ob; ob += nDst[r] + 1;
          ba.csrBase[r]  = cb; cb += E[r];
          ba.padBase[r]  = pb; pb += nb * (1 << shiftR[r]) * (PADG - 1);
      }
      ba.ablockBase[6] = ab; ba.binBase[6] = gb;
      totBins = gb; padTot = pb; }
    int* csr = (int*)alloc((size_t)(4000000 + padTot) * 4);

    // ---- CSR build (once, reused by all layers)
    hipMemsetAsync(binCnt, 0, totBins * 4, stream);
    bincount_k<<<ba.ablockBase[6], 256, 0, stream>>>(ba, binCnt);
    binscan_k<<<1, 1024, 0, stream>>>(binCnt, binOffs, binCur, totBins);
    binscat_k<<<ba.ablockBase[6], 256, 0, stream>>>(ba, binCur, staging);
    binplace2_k<<<totBins, 256, 0, stream>>>(ba, binOffs, staging, offs, poffs, csr);

    // zero rows (after staging consumed), weights, h0
    hipMemsetAsync(hA + (size_t)NTOT * H, 0, H * 2, stream);
    hipMemsetAsync(hB + (size_t)NTOT * H, 0, H * 2, stream);
    prep_w_k<<<36, 256, 0, stream>>>(Wl, Wr, b, WlT, WsumT, bsum);
    cvt_x_k<<<(NTOT * H / 8 + 255) / 256, 256, 0, stream>>>(x[0], x[1], x[2], hA);

    const size_t tOff[3] = {0, (size_t)NC_N * H, (size_t)(NC_N + NM_N) * H};
    ushort* hb[2] = {hA, hB};

    int cur = 0;
    for (int l = 0; l < 4; ++l) {
        ushort* hsrc = hb[cur];
        ushort* hdst = hb[cur ^ 1];

        AggArgs aa;
        int aggBlocks = 0;
        for (int t = 0; t < 3; ++t) {
            int rA = relA[t], rB = relB[t];
            aa.src[2 * t]      = hsrc + tOff[srcType[rA]];
            aa.offs[2 * t]     = offs + ba.offsBase[rA];
            aa.poffs[2 * t]    = poffs + ba.offsBase[rA];
            aa.out[2 * t]      = aggA[t];
            aa.src[2 * t + 1]  = hsrc + tOff[srcType[rB]];
            aa.offs[2 * t + 1] = offs + ba.offsBase[rB];
            aa.poffs[2 * t + 1]= poffs + ba.offsBase[rB];
            aa.out[2 * t + 1]  = aggB[t];
            aa.n[t] = nNode[t];
            aa.halfBlocks[t] = (nNode[t] + 3) / 4;
            aa.blockBase[t] = aggBlocks;
            aggBlocks += 2 * aa.halfBlocks[t];
        }
        aa.blockBase[3] = aggBlocks;
        agg_all_k<<<aggBlocks, 256, 0, stream>>>(aa, csr);

        GemmArgs ga;
        int gemmBlocks = 0;
        for (int t = 0; t < 3; ++t) {
            int rA = relA[t], rB = relB[t];
            ga.A1[t] = aggA[t]; ga.W1[t] = WlT + (size_t)(l * 6 + rA) * H * H;
            ga.A2[t] = aggB[t]; ga.W2[t] = WlT + (size_t)(l * 6 + rB) * H * H;
            ga.A3[t] = hsrc + tOff[t];
            ga.W3[t] = WsumT + (size_t)(l * 3 + t) * H * H;
            ga.bias[t] = bsum + (size_t)(l * 3 + t) * H;
            ga.out[t] = (l < 3) ? (void*)(hdst + tOff[t]) : (void*)(outp + tOff[t]);
            ga.n[t] = nNode[t];
            ga.blockBase[t] = gemmBlocks;
            gemmBlocks += (nNode[t] + 127) / 128;
        }
        ga.blockBase[3] = gemmBlocks;
        ga.mode = (l < 3) ? 0 : 1;
        gemm_all_k<<<gemmBlocks, 256, 0, stream>>>(ga);

        cur ^= 1;
    }
}

// Round 10
// 824.045 us; speedup vs baseline: 4.0982x; 1.0134x over previous
//
#include <hip/hip_runtime.h>
#include <hip/hip_bf16.h>

// HeteroGraphSAGE on MI355X — round 9 (identical resubmit of round 8; that
// round's bench died with "MI355X container failed twice" — infra, no data).
// Round-7 profile: agg_all_k 4x127us = 61% (VALUBusy 60%); ~half the VALU
// stream is 64-bit address arithmetic. Change (agg only): 32-bit byte-offset
// addressing (all tables < 27MB) -> saddr-form global loads; csr index loads
// use one byte-cursor add per iter + immediate offsets. Everything else
// unchanged from round 7.

#define NC_N 50000
#define NM_N 30000
#define ND_N 10000
#define NTOT 90000
#define H    128
#define PADG 16   // csr segment padding granularity

typedef __attribute__((ext_vector_type(8))) short short8;
typedef __attribute__((ext_vector_type(4))) float f32x4;

__device__ __forceinline__ ushort f2bf(float f) {
    uint u = __float_as_uint(f);
    return (ushort)((u + 0x7fffu + ((u >> 16) & 1u)) >> 16);   // RNE
}
__device__ __forceinline__ float bflo(uint v) { return __uint_as_float(v << 16); }
__device__ __forceinline__ float bfhi(uint v) { return __uint_as_float(v & 0xffff0000u); }

// ---------------------------------------------------------------- CSR build
#define ACHUNK 2048   // edges per phase-A block

struct BuildArgs {
    const int* dstp[6];
    const int* srcp[6];
    int ablockBase[7];   // prefix over ceil(E/ACHUNK)
    int binBase[7];      // prefix over nBins
    int E[6];
    int offsBase[6];
    int csrBase[6];
    int nDst[6];
    int shift[6];
    int padBase[6];      // cumulative pad allowance before relation r
    int zIdx[6];         // per-relation zero-row index (rel-local)
};

// bin-level histogram (LDS per block, one global atomic per (block,bin))
__global__ __launch_bounds__(256)
void bincount_k(BuildArgs a, int* __restrict__ binCnt) {
    __shared__ int hist[128];
    int blk = blockIdx.x, r = 0;
    #pragma unroll
    for (int k = 1; k <= 5; ++k) if (blk >= a.ablockBase[k]) r = k;
    const int i0 = (blk - a.ablockBase[r]) * ACHUNK;
    const int E = a.E[r], sh = a.shift[r];
    const int tid = threadIdx.x;
    if (tid < 128) hist[tid] = 0;
    __syncthreads();
    #pragma unroll
    for (int k = 0; k < 8; ++k) {
        int i = i0 + k * 256 + tid;
        if (i < E) atomicAdd(&hist[a.dstp[r][i] >> sh], 1);
    }
    __syncthreads();
    if (tid < 128 && hist[tid] > 0)
        atomicAdd(&binCnt[a.binBase[r] + tid], hist[tid]);
}

// single-block scan over all bins (raw edge counts; csrBase folds in)
__global__ void binscan_k(const int* __restrict__ binCnt, int* __restrict__ binOffs,
                          int* __restrict__ binCur, int totBins) {
    __shared__ int buf[1024];
    int tid = threadIdx.x;
    int v = (tid < totBins) ? binCnt[tid] : 0;
    buf[tid] = v;
    __syncthreads();
    #pragma unroll
    for (int off = 1; off < 1024; off <<= 1) {
        int t = (tid >= off) ? buf[tid - off] : 0;
        __syncthreads();
        buf[tid] += t;
        __syncthreads();
    }
    if (tid < totBins) {
        int excl = buf[tid] - v;
        binOffs[tid] = excl;
        binCur[tid]  = excl;
        if (tid == totBins - 1) binOffs[totBins] = buf[tid];
    }
}

// phase A: scatter (src,dst) pairs into bin-ordered staging
__global__ __launch_bounds__(256)
void binscat_k(BuildArgs a, int* __restrict__ binCur, int2* __restrict__ staging) {
    __shared__ int hist[128], hbase[128], hcur[128];
    int blk = blockIdx.x, r = 0;
    #pragma unroll
    for (int k = 1; k <= 5; ++k) if (blk >= a.ablockBase[k]) r = k;
    const int i0 = (blk - a.ablockBase[r]) * ACHUNK;
    const int E = a.E[r], sh = a.shift[r];
    const int tid = threadIdx.x;
    if (tid < 128) { hist[tid] = 0; hcur[tid] = 0; }
    __syncthreads();
    int d[8], s[8], bn[8];
    bool ok[8];
    #pragma unroll
    for (int k = 0; k < 8; ++k) {
        int i = i0 + k * 256 + tid;
        ok[k] = (i < E);
        if (ok[k]) {
            d[k] = a.dstp[r][i];
            s[k] = a.srcp[r][i];
            bn[k] = d[k] >> sh;
            atomicAdd(&hist[bn[k]], 1);
        }
    }
    __syncthreads();
    if (tid < 128 && hist[tid] > 0)
        hbase[tid] = atomicAdd(&binCur[a.binBase[r] + tid], hist[tid]);
    __syncthreads();
    #pragma unroll
    for (int k = 0; k < 8; ++k) {
        if (ok[k]) {
            int lr = atomicAdd(&hcur[bn[k]], 1);
            staging[hbase[bn[k]] + lr] = make_int2(s[k], d[k]);
        }
    }
}

// phase B: one block per bin. LDS node-count; raw scan (-> offs for degree);
// padded scan (-> poffs, global padded csr positions); pad-fill zero indices;
// place real edges via LDS cursors.
__global__ __launch_bounds__(256)
void binplace2_k(BuildArgs a, const int* __restrict__ binOffs,
                 const int2* __restrict__ staging,
                 int* __restrict__ offsAll, int* __restrict__ poffsAll,
                 int* __restrict__ csr) {
    __shared__ int cnt[512];
    __shared__ int sbuf[512];
    int g = blockIdx.x, r = 0;
    #pragma unroll
    for (int k = 1; k <= 5; ++k) if (g >= a.binBase[k]) r = k;
    const int b = g - a.binBase[r];
    const int sh = a.shift[r];
    const int dlo = b << sh;
    const int dhi = min(dlo + (1 << sh), a.nDst[r]);
    const int nd = dhi - dlo;
    const int tid = threadIdx.x;
    const int i0 = tid, i1 = tid + 256;
    cnt[i0] = 0; cnt[i1] = 0;
    __syncthreads();
    const int eBase = binOffs[g];
    const int eEnd  = binOffs[g + 1];
    for (int i = eBase + tid; i < eEnd; i += 256)
        atomicAdd(&cnt[staging[i].y - dlo], 1);
    __syncthreads();
    const int c0 = cnt[i0], c1 = cnt[i1];
    // raw exclusive scan
    sbuf[i0] = c0; sbuf[i1] = c1;
    __syncthreads();
    #pragma unroll
    for (int off = 1; off < 512; off <<= 1) {
        int t0 = (i0 >= off) ? sbuf[i0 - off] : 0;
        int t1 = (i1 >= off) ? sbuf[i1 - off] : 0;
        __syncthreads();
        sbuf[i0] += t0; sbuf[i1] += t1;
        __syncthreads();
    }
    const int rawe0 = sbuf[i0] - c0, rawe1 = sbuf[i1] - c1;
    // padded exclusive scan
    const int p0c = (c0 + PADG - 1) & ~(PADG - 1);
    const int p1c = (c1 + PADG - 1) & ~(PADG - 1);
    sbuf[i0] = p0c; sbuf[i1] = p1c;
    __syncthreads();
    #pragma unroll
    for (int off = 1; off < 512; off <<= 1) {
        int t0 = (i0 >= off) ? sbuf[i0 - off] : 0;
        int t1 = (i1 >= off) ? sbuf[i1 - off] : 0;
        __syncthreads();
        sbuf[i0] += t0; sbuf[i1] += t1;
        __syncthreads();
    }
    const int pe0 = sbuf[i0] - p0c, pe1 = sbuf[i1] - p1c;
    const int eRel = eBase - a.csrBase[r];
    const int pBin = eBase + a.padBase[r] + b * ((1 << sh) * (PADG - 1));
    const int zI = a.zIdx[r];
    if (i0 < nd) {
        offsAll[a.offsBase[r] + dlo + i0]  = eRel + rawe0;
        poffsAll[a.offsBase[r] + dlo + i0] = pBin + pe0;
        for (int k = c0; k < p0c; ++k) csr[pBin + pe0 + k] = zI;
    }
    if (i1 < nd) {
        offsAll[a.offsBase[r] + dlo + i1]  = eRel + rawe1;
        poffsAll[a.offsBase[r] + dlo + i1] = pBin + pe1;
        for (int k = c1; k < p1c; ++k) csr[pBin + pe1 + k] = zI;
    }
    if (tid == 0 && dhi == a.nDst[r])
        offsAll[a.offsBase[r] + a.nDst[r]] = eRel + (eEnd - eBase);
    __syncthreads();
    if (i0 < nd) cnt[i0] = pBin + pe0;
    if (i1 < nd) cnt[i1] = pBin + pe1;
    __syncthreads();
    for (int i = eBase + tid; i < eEnd; i += 256) {
        int2 pv = staging[i];
        int pos = atomicAdd(&cnt[pv.y - dlo], 1);
        csr[pos] = pv.x;
    }
}

// ---------------------------------------------- weight prep: bf16 + transpose
__global__ void prep_w_k(const float* __restrict__ Wl, const float* __restrict__ Wr,
                         const float* __restrict__ b,
                         ushort* __restrict__ WlT, ushort* __restrict__ WsumT,
                         float* __restrict__ bsum) {
    const int rA[3] = {3, 0, 1}, rB[3] = {5, 4, 2};
    int blk = blockIdx.x, tid = threadIdx.x;
    int nr = tid >> 1;
    int k0 = (tid & 1) * 64;
    if (blk < 24) {
        const float* src = Wl + (size_t)blk * 16384;
        ushort* dst = WlT + (size_t)blk * 16384;
        for (int k = k0; k < k0 + 64; ++k)
            dst[nr * 128 + k] = f2bf(src[k * 128 + nr]);
    } else {
        int lt = blk - 24, l = lt / 3, t = lt % 3;
        const float* sA = Wr + (size_t)(l * 6 + rA[t]) * 16384;
        const float* sB = Wr + (size_t)(l * 6 + rB[t]) * 16384;
        ushort* dst = WsumT + (size_t)lt * 16384;
        for (int k = k0; k < k0 + 64; ++k)
            dst[nr * 128 + k] = f2bf(sA[k * 128 + nr] + sB[k * 128 + nr]);
        if (tid < 128)
            bsum[lt * 128 + tid] = b[(l * 6 + rA[t]) * 128 + tid] +
                                   b[(l * 6 + rB[t]) * 128 + tid];
    }
}

// ------------------------------------------------------- x -> bf16 h0
__global__ void cvt_x_k(const float* __restrict__ xc, const float* __restrict__ xm,
                        const float* __restrict__ xd, ushort* __restrict__ h) {
    int i = blockIdx.x * 256 + threadIdx.x;
    const int tot = NTOT * H / 8;
    if (i >= tot) return;
    size_t base = (size_t)i * 8;
    int row = (int)(base >> 7);
    const float* src; size_t local;
    if (row < NC_N) { src = xc; local = base; }
    else if (row < NC_N + NM_N) { src = xm; local = base - (size_t)NC_N * H; }
    else { src = xd; local = base - (size_t)(NC_N + NM_N) * H; }
    float4 v0 = *(const float4*)(src + local);
    float4 v1 = *(const float4*)(src + local + 4);
    uint4 o;
    o.x = (uint)f2bf(v0.x) | ((uint)f2bf(v0.y) << 16);
    o.y = (uint)f2bf(v0.z) | ((uint)f2bf(v0.w) << 16);
    o.z = (uint)f2bf(v1.x) | ((uint)f2bf(v1.y) << 16);
    o.w = (uint)f2bf(v1.z) | ((uint)f2bf(v1.w) << 16);
    *(uint4*)(h + base) = o;
}

// ----------------------------------------------------------- segment mean
// All 6 relations in one dispatch. Padded csr -> branch-free MLP-8 loop.
// v4: 32-bit byte-offset addressing (saddr-form loads); csr cursor kept in
// bytes, per-load deltas in the immediate offset field.
struct AggArgs {
    const ushort* src[6];
    const int* offs[6];    // raw offsets (degree)
    const int* poffs[6];   // padded global start positions
    ushort* out[6];
    int n[3];
    int blockBase[4];
    int halfBlocks[3];
};

__global__ __launch_bounds__(256)
void agg_all_k(AggArgs ga, const int* __restrict__ csr) {
    const int b = blockIdx.x;
    const int t = (b >= ga.blockBase[2]) ? 2 : (b >= ga.blockBase[1]) ? 1 : 0;
    const int local = b - ga.blockBase[t];
    const int isB = (local >= ga.halfBlocks[t]) ? 1 : 0;
    const int ridx = 2 * t + isB;
    const char* __restrict__ srcB = (const char*)ga.src[ridx];
    const int* __restrict__ offs  = ga.offs[ridx];
    const int* __restrict__ poffs = ga.poffs[ridx];
    char* __restrict__ outB       = (char*)ga.out[ridx];
    const char* __restrict__ csrB = (const char*)csr;
    const int n = ga.n[t];
    const int w = (local - isB * ga.halfBlocks[t]) * 4 + (int)(threadIdx.x >> 6);
    if (w >= n) return;
    const int lane = threadIdx.x & 63;
    const int half = lane >> 5;
    const int lh   = lane & 31;
    const int deg  = offs[w + 1] - offs[w];
    const uint ps  = (uint)poffs[w];
    const uint lhB = (uint)(lh << 3);          // byte offset within 256B row
    uint jb   = (ps << 2) + (uint)(half << 2); // byte cursor into csr
    const uint jbEnd = jb + (uint)(((deg + PADG - 1) & ~(PADG - 1)) << 2);

    float a0 = 0.f, a1 = 0.f, a2 = 0.f, a3 = 0.f;
    for (; jb < jbEnd; jb += 64) {
        uint i0 = *(const uint*)(csrB + jb + 0);
        uint i1 = *(const uint*)(csrB + jb + 8);
        uint i2 = *(const uint*)(csrB + jb + 16);
        uint i3 = *(const uint*)(csrB + jb + 24);
        uint i4 = *(const uint*)(csrB + jb + 32);
        uint i5 = *(const uint*)(csrB + jb + 40);
        uint i6 = *(const uint*)(csrB + jb + 48);
        uint i7 = *(const uint*)(csrB + jb + 56);
        uint2 v0 = *(const uint2*)(srcB + ((i0 << 8) + lhB));
        uint2 v1 = *(const uint2*)(srcB + ((i1 << 8) + lhB));
        uint2 v2 = *(const uint2*)(srcB + ((i2 << 8) + lhB));
        uint2 v3 = *(const uint2*)(srcB + ((i3 << 8) + lhB));
        uint2 v4 = *(const uint2*)(srcB + ((i4 << 8) + lhB));
        uint2 v5 = *(const uint2*)(srcB + ((i5 << 8) + lhB));
        uint2 v6 = *(const uint2*)(srcB + ((i6 << 8) + lhB));
        uint2 v7 = *(const uint2*)(srcB + ((i7 << 8) + lhB));
        a0 += bflo(v0.x) + bflo(v1.x) + bflo(v2.x) + bflo(v3.x)
            + bflo(v4.x) + bflo(v5.x) + bflo(v6.x) + bflo(v7.x);
        a1 += bfhi(v0.x) + bfhi(v1.x) + bfhi(v2.x) + bfhi(v3.x)
            + bfhi(v4.x) + bfhi(v5.x) + bfhi(v6.x) + bfhi(v7.x);
        a2 += bflo(v0.y) + bflo(v1.y) + bflo(v2.y) + bflo(v3.y)
            + bflo(v4.y) + bflo(v5.y) + bflo(v6.y) + bflo(v7.y);
        a3 += bfhi(v0.y) + bfhi(v1.y) + bfhi(v2.y) + bfhi(v3.y)
            + bfhi(v4.y) + bfhi(v5.y) + bfhi(v6.y) + bfhi(v7.y);
    }
    a0 += __shfl_xor(a0, 32);
    a1 += __shfl_xor(a1, 32);
    a2 += __shfl_xor(a2, 32);
    a3 += __shfl_xor(a3, 32);
    if (half == 0) {
        const float inv = 1.0f / fmaxf((float)deg, 1.0f);
        uint2 o;
        o.x = (uint)f2bf(a0 * inv) | ((uint)f2bf(a1 * inv) << 16);
        o.y = (uint)f2bf(a2 * inv) | ((uint)f2bf(a3 * inv) << 16);
        *(uint2*)(outB + (((uint)w << 8) + lhB)) = o;
    }
}

// ------------------------------------------------------------ MFMA GEMM
struct GemmArgs {
    const ushort* A1[3]; const ushort* W1[3];
    const ushort* A2[3]; const ushort* W2[3];
    const ushort* A3[3]; const ushort* W3[3];
    const float* bias[3];
    void* out[3];
    int n[3];
    int blockBase[4];
    int mode;
};

__global__ __launch_bounds__(256)
void gemm_all_k(GemmArgs ga) {
    __shared__ ushort As[128][40];
    __shared__ ushort Bs[128][40];
    const int b = blockIdx.x;
    const int t = (b >= ga.blockBase[2]) ? 2 : (b >= ga.blockBase[1]) ? 1 : 0;
    const int tid  = threadIdx.x;
    const int wave = tid >> 6, lane = tid & 63;
    const int lr = lane & 15, lk = lane >> 4;
    const int row0 = (b - ga.blockBase[t]) * 128;
    const int n = ga.n[t];

    f32x4 acc[2][8];
    #pragma unroll
    for (int i = 0; i < 2; ++i)
        #pragma unroll
        for (int j = 0; j < 8; ++j) acc[i][j] = (f32x4)0.f;

    const ushort* Ap[3] = {ga.A1[t], ga.A2[t], ga.A3[t]};
    const ushort* Wp[3] = {ga.W1[t], ga.W2[t], ga.W3[t]};

    const int rs = tid >> 2;
    const int kb = (tid & 3) * 8;

    for (int term = 0; term < 3; ++term) {
        const ushort* A = Ap[term];
        const ushort* W = Wp[term];
        #pragma unroll 1
        for (int k0 = 0; k0 < 128; k0 += 32) {
            #pragma unroll
            for (int p = 0; p < 2; ++p) {
                int rr = rs + p * 64;
                int gr = row0 + rr;
                short8 av = (short8)0;
                if (gr < n) av = *(const short8*)(A + (size_t)gr * 128 + k0 + kb);
                *(short8*)&As[rr][kb] = av;
                short8 wv = *(const short8*)(W + (size_t)rr * 128 + k0 + kb);
                *(short8*)&Bs[rr][kb] = wv;
            }
            __syncthreads();
            short8 af0 = *(const short8*)&As[wave * 32 + lr][lk * 8];
            short8 af1 = *(const short8*)&As[wave * 32 + 16 + lr][lk * 8];
            #pragma unroll
            for (int nt = 0; nt < 8; ++nt) {
                short8 bf = *(const short8*)&Bs[nt * 16 + lr][lk * 8];
                acc[0][nt] = __builtin_amdgcn_mfma_f32_16x16x32_bf16(af0, bf, acc[0][nt], 0, 0, 0);
                acc[1][nt] = __builtin_amdgcn_mfma_f32_16x16x32_bf16(af1, bf, acc[1][nt], 0, 0, 0);
            }
            __syncthreads();
        }
    }
    float bv[8];
    #pragma unroll
    for (int nt = 0; nt < 8; ++nt) bv[nt] = ga.bias[t][nt * 16 + lr];

    if (ga.mode == 0) {
        ushort* outp = (ushort*)ga.out[t];
        #pragma unroll
        for (int mt = 0; mt < 2; ++mt) {
            #pragma unroll
            for (int nt = 0; nt < 8; ++nt) {
                int col = nt * 16 + lr;
                #pragma unroll
                for (int r = 0; r < 4; ++r) {
                    int row = row0 + wave * 32 + mt * 16 + lk * 4 + r;
                    if (row < n) {
                        float v = fmaxf(0.5f * (acc[mt][nt][r] + bv[nt]), 0.f);
                        outp[(size_t)row * 128 + col] = f2bf(v);
                    }
                }
            }
        }
    } else {
        float* outp = (float*)ga.out[t];
        #pragma unroll
        for (int mt = 0; mt < 2; ++mt) {
            #pragma unroll
            for (int r = 0; r < 4; ++r) {
                float v[8]; float ss = 0.f;
                #pragma unroll
                for (int nt = 0; nt < 8; ++nt) {
                    v[nt] = 0.5f * (acc[mt][nt][r] + bv[nt]);
                    ss += v[nt] * v[nt];
                }
                ss += __shfl_xor(ss, 1);
                ss += __shfl_xor(ss, 2);
                ss += __shfl_xor(ss, 4);
                ss += __shfl_xor(ss, 8);
                float scale = 1.0f / fmaxf(sqrtf(ss), 1e-12f);
                int row = row0 + wave * 32 + mt * 16 + lk * 4 + r;
                if (row < n) {
                    #pragma unroll
                    for (int nt = 0; nt < 8; ++nt)
                        outp[(size_t)row * 128 + nt * 16 + lr] = v[nt] * scale;
                }
            }
        }
    }
}

// ---------------------------------------------------------------- launch
extern "C" void kernel_launch(void* const* d_in, const int* in_sizes, int n_in,
                              void* d_out, int out_size, void* d_ws, size_t ws_size,
                              hipStream_t stream) {
    const float* x[3] = {(const float*)d_in[0], (const float*)d_in[1], (const float*)d_in[2]};
    const int* srcp[6] = {(const int*)d_in[3], (const int*)d_in[5], (const int*)d_in[7],
                          (const int*)d_in[9], (const int*)d_in[11], (const int*)d_in[13]};
    const int* dstp[6] = {(const int*)d_in[4], (const int*)d_in[6], (const int*)d_in[8],
                          (const int*)d_in[10], (const int*)d_in[12], (const int*)d_in[14]};
    const float* Wl = (const float*)d_in[15];
    const float* Wr = (const float*)d_in[16];
    const float* b  = (const float*)d_in[17];
    float* outp = (float*)d_out;

    const int nNode[3]   = {NC_N, NM_N, ND_N};
    const int E[6]       = {800000, 400000, 800000, 800000, 400000, 800000};
    const int nDst[6]    = {NM_N, ND_N, ND_N, NC_N, NM_N, NC_N};
    const int shiftR[6]  = {8, 7, 7, 9, 8, 9};
    const int srcType[6] = {0, 1, 0, 1, 2, 2};
    const int relA[3] = {3, 0, 1}, relB[3] = {5, 4, 2};
    const int srcRowOff[3] = {0, NC_N, NC_N + NM_N};

    // ---- workspace carve-up (256B aligned)
    char* p = (char*)d_ws;
    auto alloc = [&](size_t bytes) -> char* {
        char* r = p; p += (bytes + 255) & ~(size_t)255; return r;
    };
    ushort* hA    = (ushort*)alloc((size_t)(NTOT + 1) * H * 2);  // +1 zero row
    ushort* hB    = (ushort*)alloc((size_t)(NTOT + 1) * H * 2);
    ushort* aggA[3], * aggB[3];
    for (int t = 0; t < 3; ++t) {
        aggA[t] = (ushort*)alloc((size_t)nNode[t] * H * 2);
        aggB[t] = (ushort*)alloc((size_t)nNode[t] * H * 2);
    }
    ushort* WlT   = (ushort*)alloc((size_t)24 * H * H * 2);
    ushort* WsumT = (ushort*)alloc((size_t)12 * H * H * 2);
    float*  bsum  = (float*)alloc((size_t)12 * H * 4);
    int*    offs  = (int*)alloc((size_t)180006 * 4);
    int*    poffs = (int*)alloc((size_t)180006 * 4);
    int*    binCnt  = (int*)alloc((size_t)1024 * 4);
    int*    binOffs = (int*)alloc((size_t)1025 * 4);
    int*    binCur  = (int*)alloc((size_t)1024 * 4);
    // staging (32MB) aliases hA+hB (46MB) — consumed before cvt_x/zero-row
    int2*   staging = (int2*)hA;

    BuildArgs ba;
    int totBins = 0, padTot = 0;
    { int ob = 0, cb = 0, ab = 0, gb = 0, pb = 0;
      for (int r = 0; r < 6; ++r) {
          ba.dstp[r] = dstp[r]; ba.srcp[r] = srcp[r];
          ba.E[r] = E[r]; ba.nDst[r] = nDst[r]; ba.shift[r] = shiftR[r];
          ba.zIdx[r] = NTOT - srcRowOff[srcType[r]];
          ba.ablockBase[r] = ab; ab += (E[r] + ACHUNK - 1) / ACHUNK;
          int nb = (nDst[r] + (1 << shiftR[r]) - 1) >> shiftR[r];
          ba.binBase[r] = gb; gb += nb;
          ba.offsBase[r] = ob; ob += nDst[r] + 1;
          ba.csrBase[r]  = cb; cb += E[r];
          ba.padBase[r]  = pb; pb += nb * (1 << shiftR[r]) * (PADG - 1);
      }
      ba.ablockBase[6] = ab; ba.binBase[6] = gb;
      totBins = gb; padTot = pb; }
    int* csr = (int*)alloc((size_t)(4000000 + padTot) * 4);

    // ---- CSR build (once, reused by all layers)
    hipMemsetAsync(binCnt, 0, totBins * 4, stream);
    bincount_k<<<ba.ablockBase[6], 256, 0, stream>>>(ba, binCnt);
    binscan_k<<<1, 1024, 0, stream>>>(binCnt, binOffs, binCur, totBins);
    binscat_k<<<ba.ablockBase[6], 256, 0, stream>>>(ba, binCur, staging);
    binplace2_k<<<totBins, 256, 0, stream>>>(ba, binOffs, staging, offs, poffs, csr);

    // zero rows (after staging consumed), weights, h0
    hipMemsetAsync(hA + (size_t)NTOT * H, 0, H * 2, stream);
    hipMemsetAsync(hB + (size_t)NTOT * H, 0, H * 2, stream);
    prep_w_k<<<36, 256, 0, stream>>>(Wl, Wr, b, WlT, WsumT, bsum);
    cvt_x_k<<<(NTOT * H / 8 + 255) / 256, 256, 0, stream>>>(x[0], x[1], x[2], hA);

    const size_t tOff[3] = {0, (size_t)NC_N * H, (size_t)(NC_N + NM_N) * H};
    ushort* hb[2] = {hA, hB};

    int cur = 0;
    for (int l = 0; l < 4; ++l) {
        ushort* hsrc = hb[cur];
        ushort* hdst = hb[cur ^ 1];

        AggArgs aa;
        int aggBlocks = 0;
        for (int t = 0; t < 3; ++t) {
            int rA = relA[t], rB = relB[t];
            aa.src[2 * t]      = hsrc + tOff[srcType[rA]];
            aa.offs[2 * t]     = offs + ba.offsBase[rA];
            aa.poffs[2 * t]    = poffs + ba.offsBase[rA];
            aa.out[2 * t]      = aggA[t];
            aa.src[2 * t + 1]  = hsrc + tOff[srcType[rB]];
            aa.offs[2 * t + 1] = offs + ba.offsBase[rB];
            aa.poffs[2 * t + 1]= poffs + ba.offsBase[rB];
            aa.out[2 * t + 1]  = aggB[t];
            aa.n[t] = nNode[t];
            aa.halfBlocks[t] = (nNode[t] + 3) / 4;
            aa.blockBase[t] = aggBlocks;
            aggBlocks += 2 * aa.halfBlocks[t];
        }
        aa.blockBase[3] = aggBlocks;
        agg_all_k<<<aggBlocks, 256, 0, stream>>>(aa, csr);

        GemmArgs ga;
        int gemmBlocks = 0;
        for (int t = 0; t < 3; ++t) {
            int rA = relA[t], rB = relB[t];
            ga.A1[t] = aggA[t]; ga.W1[t] = WlT + (size_t)(l * 6 + rA) * H * H;
            ga.A2[t] = aggB[t]; ga.W2[t] = WlT + (size_t)(l * 6 + rB) * H * H;
            ga.A3[t] = hsrc + tOff[t];
            ga.W3[t] = WsumT + (size_t)(l * 3 + t) * H * H;
            ga.bias[t] = bsum + (size_t)(l * 3 + t) * H;
            ga.out[t] = (l < 3) ? (void*)(hdst + tOff[t]) : (void*)(outp + tOff[t]);
            ga.n[t] = nNode[t];
            ga.blockBase[t] = gemmBlocks;
            gemmBlocks += (nNode[t] + 127) / 128;
        }
        ga.blockBase[3] = gemmBlocks;
        ga.mode = (l < 3) ? 0 : 1;
        gemm_all_k<<<gemmBlocks, 256, 0, stream>>>(ga);

        cur ^= 1;
    }
}